// Round 1
// baseline (389.540 us; speedup 1.0000x reference)
//
#include <hip/hip_runtime.h>
#include <math.h>

#define NN 50000
#define CH 128
#define NG 512
#define OCH 16

// ---------------- CSR build ----------------

__global__ void count_dst_k(const int* __restrict__ dst, int* __restrict__ cnt, int e) {
    int i = blockIdx.x * blockDim.x + threadIdx.x;
    if (i < e) atomicAdd(&cnt[dst[i]], 1);
}

// exclusive prefix sum of n (<= 1024*per) ints, single block, strip-per-thread
__global__ __launch_bounds__(1024) void scan_big_k(const int* __restrict__ cnt, int* __restrict__ out, int n) {
    __shared__ int ssum[1024];
    int t = threadIdx.x;
    int per = (n + 1023) >> 10;
    int lo = t * per; if (lo > n) lo = n;
    int hi = lo + per; if (hi > n) hi = n;
    int s = 0;
    for (int i = lo; i < hi; ++i) s += cnt[i];
    ssum[t] = s;
    __syncthreads();
    for (int off = 1; off < 1024; off <<= 1) {
        int v = (t >= off) ? ssum[t - off] : 0;
        __syncthreads();
        ssum[t] += v;
        __syncthreads();
    }
    int run = ssum[t] - s;   // exclusive prefix of strips
    for (int i = lo; i < hi; ++i) { out[i] = run; run += cnt[i]; }
    if (lo < n && hi == n) out[n] = run;   // total
}

__global__ void dinv_k(const int* __restrict__ cnt, float* __restrict__ dinv, int n) {
    int i = blockIdx.x * blockDim.x + threadIdx.x;
    if (i < n) dinv[i] = rsqrtf((float)cnt[i] + 1.0f);   // +1 self-loop
}

__global__ void fill_csr_k(const int* __restrict__ src, const int* __restrict__ dst,
                           const int* __restrict__ row_start, int* __restrict__ cursor,
                           int* __restrict__ csr_src, int e) {
    int i = blockIdx.x * blockDim.x + threadIdx.x;
    if (i < e) {
        int d = dst[i];
        int pos = atomicAdd(&cursor[d], 1);
        csr_src[row_start[d] + pos] = src[i];
    }
}

__global__ void hist_batch_k(const int* __restrict__ batch, int* __restrict__ g, int n) {
    int i = blockIdx.x * blockDim.x + threadIdx.x;
    if (i < n) atomicAdd(&g[batch[i]], 1);
}

__global__ __launch_bounds__(512) void scan_gr_k(const int* __restrict__ cnt, int* __restrict__ out) {
    __shared__ int s[512];
    int t = threadIdx.x;
    int v = cnt[t];
    s[t] = v;
    __syncthreads();
    for (int off = 1; off < 512; off <<= 1) {
        int u = (t >= off) ? s[t - off] : 0;
        __syncthreads();
        s[t] += u;
        __syncthreads();
    }
    out[t] = s[t] - v;
    if (t == 511) out[512] = s[511];
}

// ---------------- GEMM [n x 128] @ [128 x 128], epilogue scale by dinv[row] ----------------

__global__ __launch_bounds__(256) void gemm_scale_k(const float* __restrict__ A, const float* __restrict__ W,
                                                    const float* __restrict__ dinv, float* __restrict__ C, int n) {
    __shared__ float xs[64][128];
    int rowBase = blockIdx.x * 64;
    const float4* A4 = (const float4*)A;
    for (int i = threadIdx.x; i < 64 * 32; i += 256) {
        int r = i >> 5, c = i & 31;
        int row = rowBase + r;
        float4 v = make_float4(0.f, 0.f, 0.f, 0.f);
        if (row < n) v = A4[(size_t)row * 32 + c];
        ((float4*)xs[r])[c] = v;
    }
    __syncthreads();
    int tx = threadIdx.x & 31;   // col group: cols 4*tx..4*tx+3
    int ty = threadIdx.x >> 5;   // rows ty*8 .. ty*8+7
    float4 acc[8];
#pragma unroll
    for (int r = 0; r < 8; ++r) acc[r] = make_float4(0.f, 0.f, 0.f, 0.f);
    const float4* W4 = (const float4*)W;
    for (int kk = 0; kk < 32; ++kk) {
        float4 xa[8];
#pragma unroll
        for (int r = 0; r < 8; ++r) xa[r] = ((float4*)xs[ty * 8 + r])[kk];
#pragma unroll
        for (int j = 0; j < 4; ++j) {
            float4 w = W4[(size_t)(kk * 4 + j) * 32 + tx];
#pragma unroll
            for (int r = 0; r < 8; ++r) {
                float a = (j == 0) ? xa[r].x : (j == 1) ? xa[r].y : (j == 2) ? xa[r].z : xa[r].w;
                acc[r].x = fmaf(a, w.x, acc[r].x);
                acc[r].y = fmaf(a, w.y, acc[r].y);
                acc[r].z = fmaf(a, w.z, acc[r].z);
                acc[r].w = fmaf(a, w.w, acc[r].w);
            }
        }
    }
    float4* C4 = (float4*)C;
#pragma unroll
    for (int r = 0; r < 8; ++r) {
        int row = rowBase + ty * 8 + r;
        if (row < n) {
            float dv = dinv[row];
            float4 o = acc[r];
            o.x *= dv; o.y *= dv; o.z *= dv; o.w *= dv;
            C4[(size_t)row * 32 + tx] = o;
        }
    }
}

// ---------------- aggregation: out[v] = relu(dinv[v]*(ht[v] + sum ht[src]) + b) ----------------
// ht is already row-scaled by dinv (GEMM epilogue). 32 lanes per node, float4/lane.

__global__ __launch_bounds__(256) void aggregate_k(const float* __restrict__ ht, const float* __restrict__ dinv,
                                                   const int* __restrict__ row_start, const int* __restrict__ csr_src,
                                                   const float* __restrict__ bias, float* __restrict__ out, int n) {
    int node = blockIdx.x * 8 + (threadIdx.x >> 5);
    if (node >= n) return;
    int lane = threadIdx.x & 31;
    const float4* H4 = (const float4*)ht;
    float4 acc = H4[(size_t)node * 32 + lane];   // self contribution ht[v]
    int beg = row_start[node], end = row_start[node + 1];
    for (int i = beg; i < end; ++i) {
        int s = csr_src[i];
        float4 t = H4[(size_t)s * 32 + lane];
        acc.x += t.x; acc.y += t.y; acc.z += t.z; acc.w += t.w;
    }
    float dv = dinv[node];
    float4 b = ((const float4*)bias)[lane];
    float4 o;
    o.x = fmaxf(fmaf(acc.x, dv, b.x), 0.f);
    o.y = fmaxf(fmaf(acc.y, dv, b.y), 0.f);
    o.z = fmaxf(fmaf(acc.z, dv, b.z), 0.f);
    o.w = fmaxf(fmaf(acc.w, dv, b.w), 0.f);
    ((float4*)out)[(size_t)node * 32 + lane] = o;
}

// ---------------- mean pool (batch sorted -> contiguous ranges) ----------------

__global__ __launch_bounds__(128) void pool_k(const float* __restrict__ h, const int* __restrict__ gstart,
                                              const int* __restrict__ gcnt, float* __restrict__ pooled) {
    int g = blockIdx.x;
    int t = threadIdx.x;
    int beg = gstart[g], c = gcnt[g];
    float s = 0.f;
    for (int i = 0; i < c; ++i) s += h[(size_t)(beg + i) * CH + t];
    float inv = 1.0f / fmaxf((float)c, 1.0f);
    pooled[(size_t)g * CH + t] = s * inv;
}

// ---------------- FC + sigmoid: [512x128]@[128x16] ----------------

__global__ __launch_bounds__(256) void fc_k(const float* __restrict__ pooled, const float* __restrict__ Wfc,
                                            const float* __restrict__ bfc, float* __restrict__ out) {
    __shared__ float ws[CH * OCH];
    for (int i = threadIdx.x; i < CH * OCH; i += 256) ws[i] = Wfc[i];
    __syncthreads();
    int tx = threadIdx.x & 15;   // out channel
    int gy = threadIdx.x >> 4;   // 16 graphs per block
    int g = blockIdx.x * 16 + gy;
    float acc = bfc[tx];
    const float* pr = pooled + (size_t)g * CH;
    for (int k = 0; k < CH; ++k) acc = fmaf(pr[k], ws[k * OCH + tx], acc);
    out[(size_t)g * OCH + tx] = 1.0f / (1.0f + expf(-acc));
}

extern "C" void kernel_launch(void* const* d_in, const int* in_sizes, int n_in,
                              void* d_out, int out_size, void* d_ws, size_t ws_size,
                              hipStream_t stream) {
    const float* x    = (const float*)d_in[0];
    const int*   edge = (const int*)d_in[1];
    const int*   batch= (const int*)d_in[2];
    const float* W1   = (const float*)d_in[3];
    const float* b1   = (const float*)d_in[4];
    const float* W2   = (const float*)d_in[5];
    const float* b2   = (const float*)d_in[6];
    const float* Wfc  = (const float*)d_in[7];
    const float* bfc  = (const float*)d_in[8];
    float* out = (float*)d_out;

    const int N = NN;
    const int E = in_sizes[1] / 2;
    const int* src = edge;
    const int* dst = edge + E;

    // workspace layout
    float* h      = (float*)d_ws;             // N*CH
    float* agg    = h + (size_t)N * CH;       // N*CH
    float* dinv   = agg + (size_t)N * CH;     // N
    float* pooled = dinv + N;                 // NG*CH
    int* row_counts = (int*)(pooled + (size_t)NG * CH); // N
    int* row_start  = row_counts + N;         // N+1
    int* cursor     = row_start + N + 1;      // N
    int* csr_src    = cursor + N;             // E
    int* gcnt       = csr_src + E;            // NG
    int* gstart     = gcnt + NG;              // NG+1

    hipMemsetAsync(row_counts, 0, (size_t)(3 * N + 1) * sizeof(int), stream);
    hipMemsetAsync(gcnt, 0, (size_t)NG * sizeof(int), stream);

    const int tb = 256;
    count_dst_k<<<(E + tb - 1) / tb, tb, 0, stream>>>(dst, row_counts, E);
    scan_big_k<<<1, 1024, 0, stream>>>(row_counts, row_start, N);
    dinv_k<<<(N + tb - 1) / tb, tb, 0, stream>>>(row_counts, dinv, N);
    fill_csr_k<<<(E + tb - 1) / tb, tb, 0, stream>>>(src, dst, row_start, cursor, csr_src, E);
    hist_batch_k<<<(N + tb - 1) / tb, tb, 0, stream>>>(batch, gcnt, N);
    scan_gr_k<<<1, 512, 0, stream>>>(gcnt, gstart);

    gemm_scale_k<<<(N + 63) / 64, 256, 0, stream>>>(x, W1, dinv, h, N);
    aggregate_k<<<(N + 7) / 8, 256, 0, stream>>>(h, dinv, row_start, csr_src, b1, agg, N);
    gemm_scale_k<<<(N + 63) / 64, 256, 0, stream>>>(agg, W2, dinv, h, N);
    aggregate_k<<<(N + 7) / 8, 256, 0, stream>>>(h, dinv, row_start, csr_src, b2, agg, N);
    pool_k<<<NG, 128, 0, stream>>>(agg, gstart, gcnt, pooled);
    fc_k<<<NG / 16, 256, 0, stream>>>(pooled, Wfc, bfc, out);
}

// Round 2
// 323.926 us; speedup vs baseline: 1.2026x; 1.2026x over previous
//
#include <hip/hip_runtime.h>
#include <math.h>

#define NN 50000
#define CH 128
#define NG 512
#define OCH 16
#define SCHUNK 1024

// ---------------- CSR build ----------------

__global__ void count_dst_k(const int* __restrict__ dst, int* __restrict__ cnt, int e) {
    int i = blockIdx.x * blockDim.x + threadIdx.x;
    if (i < e) atomicAdd(&cnt[dst[i]], 1);
}

// ---- 3-phase device-wide exclusive scan of n ints (n <= 1024*1024) ----
__global__ __launch_bounds__(256) void scanA_k(const int* __restrict__ cnt, int* __restrict__ part, int n) {
    __shared__ int s[256];
    int base = blockIdx.x * SCHUNK;
    int t = threadIdx.x;
    int sum = 0;
#pragma unroll
    for (int j = 0; j < 4; ++j) {
        int idx = base + t * 4 + j;
        if (idx < n) sum += cnt[idx];
    }
    s[t] = sum;
    __syncthreads();
    for (int off = 128; off > 0; off >>= 1) {
        if (t < off) s[t] += s[t + off];
        __syncthreads();
    }
    if (t == 0) part[blockIdx.x] = s[0];
}

__global__ __launch_bounds__(1024) void scanB_k(int* __restrict__ part, int nb, int* __restrict__ row_start, int n) {
    __shared__ int s[1024];
    int t = threadIdx.x;
    int v = (t < nb) ? part[t] : 0;
    s[t] = v;
    __syncthreads();
    for (int off = 1; off < 1024; off <<= 1) {
        int u = (t >= off) ? s[t - off] : 0;
        __syncthreads();
        s[t] += u;
        __syncthreads();
    }
    if (t < nb) part[t] = s[t] - v;            // exclusive scan of partials
    if (t == nb - 1) row_start[n] = s[t];      // grand total
}

__global__ __launch_bounds__(256) void scanC_k(const int* __restrict__ cnt, const int* __restrict__ part,
                                               int* __restrict__ out, int n) {
    __shared__ int s[256];
    int base = blockIdx.x * SCHUNK;
    int t = threadIdx.x;
    int v[4];
    int sum = 0;
#pragma unroll
    for (int j = 0; j < 4; ++j) {
        int idx = base + t * 4 + j;
        v[j] = (idx < n) ? cnt[idx] : 0;
        sum += v[j];
    }
    s[t] = sum;
    __syncthreads();
    for (int off = 1; off < 256; off <<= 1) {
        int u = (t >= off) ? s[t - off] : 0;
        __syncthreads();
        s[t] += u;
        __syncthreads();
    }
    int run = part[blockIdx.x] + s[t] - sum;   // exclusive prefix at this thread's first element
#pragma unroll
    for (int j = 0; j < 4; ++j) {
        int idx = base + t * 4 + j;
        if (idx < n) out[idx] = run;
        run += v[j];
    }
}

__global__ void dinv_k(const int* __restrict__ cnt, float* __restrict__ dinv, int n) {
    int i = blockIdx.x * blockDim.x + threadIdx.x;
    if (i < n) dinv[i] = rsqrtf((float)cnt[i] + 1.0f);   // +1 self-loop
}

__global__ void fill_csr_k(const int* __restrict__ src, const int* __restrict__ dst,
                           const int* __restrict__ row_start, int* __restrict__ cursor,
                           int* __restrict__ csr_src, int e) {
    int i = blockIdx.x * blockDim.x + threadIdx.x;
    if (i < e) {
        int d = dst[i];
        int pos = atomicAdd(&cursor[d], 1);
        csr_src[row_start[d] + pos] = src[i];
    }
}

__global__ void hist_batch_k(const int* __restrict__ batch, int* __restrict__ g, int n) {
    int i = blockIdx.x * blockDim.x + threadIdx.x;
    if (i < n) atomicAdd(&g[batch[i]], 1);
}

__global__ __launch_bounds__(512) void scan_gr_k(const int* __restrict__ cnt, int* __restrict__ out) {
    __shared__ int s[512];
    int t = threadIdx.x;
    int v = cnt[t];
    s[t] = v;
    __syncthreads();
    for (int off = 1; off < 512; off <<= 1) {
        int u = (t >= off) ? s[t - off] : 0;
        __syncthreads();
        s[t] += u;
        __syncthreads();
    }
    out[t] = s[t] - v;
    if (t == 511) out[512] = s[511];
}

// ---------------- GEMM [n x 128] @ [128 x 128], epilogue scale by dinv[row] ----------------

__global__ __launch_bounds__(256) void gemm_scale_k(const float* __restrict__ A, const float* __restrict__ W,
                                                    const float* __restrict__ dinv, float* __restrict__ C, int n) {
    __shared__ float xs[64][128];
    int rowBase = blockIdx.x * 64;
    const float4* A4 = (const float4*)A;
    for (int i = threadIdx.x; i < 64 * 32; i += 256) {
        int r = i >> 5, c = i & 31;
        int row = rowBase + r;
        float4 v = make_float4(0.f, 0.f, 0.f, 0.f);
        if (row < n) v = A4[(size_t)row * 32 + c];
        ((float4*)xs[r])[c] = v;
    }
    __syncthreads();
    int tx = threadIdx.x & 31;   // col group: cols 4*tx..4*tx+3
    int ty = threadIdx.x >> 5;   // rows ty*8 .. ty*8+7
    float4 acc[8];
#pragma unroll
    for (int r = 0; r < 8; ++r) acc[r] = make_float4(0.f, 0.f, 0.f, 0.f);
    const float4* W4 = (const float4*)W;
    for (int kk = 0; kk < 32; ++kk) {
        float4 xa[8];
#pragma unroll
        for (int r = 0; r < 8; ++r) xa[r] = ((float4*)xs[ty * 8 + r])[kk];
#pragma unroll
        for (int j = 0; j < 4; ++j) {
            float4 w = W4[(size_t)(kk * 4 + j) * 32 + tx];
#pragma unroll
            for (int r = 0; r < 8; ++r) {
                float a = (j == 0) ? xa[r].x : (j == 1) ? xa[r].y : (j == 2) ? xa[r].z : xa[r].w;
                acc[r].x = fmaf(a, w.x, acc[r].x);
                acc[r].y = fmaf(a, w.y, acc[r].y);
                acc[r].z = fmaf(a, w.z, acc[r].z);
                acc[r].w = fmaf(a, w.w, acc[r].w);
            }
        }
    }
    float4* C4 = (float4*)C;
#pragma unroll
    for (int r = 0; r < 8; ++r) {
        int row = rowBase + ty * 8 + r;
        if (row < n) {
            float dv = dinv[row];
            float4 o = acc[r];
            o.x *= dv; o.y *= dv; o.z *= dv; o.w *= dv;
            C4[(size_t)row * 32 + tx] = o;
        }
    }
}

// ---------------- aggregation: out[v] = relu(dinv[v]*(ht[v] + sum ht[src]) + b) ----------------
// ht is already row-scaled by dinv (GEMM epilogue). 32 lanes per node, float4/lane.

__global__ __launch_bounds__(256) void aggregate_k(const float* __restrict__ ht, const float* __restrict__ dinv,
                                                   const int* __restrict__ row_start, const int* __restrict__ csr_src,
                                                   const float* __restrict__ bias, float* __restrict__ out, int n) {
    int node = blockIdx.x * 8 + (threadIdx.x >> 5);
    if (node >= n) return;
    int lane = threadIdx.x & 31;
    const float4* H4 = (const float4*)ht;
    float4 acc = H4[(size_t)node * 32 + lane];   // self contribution ht[v]
    int beg = row_start[node], end = row_start[node + 1];
    for (int i = beg; i < end; ++i) {
        int s = csr_src[i];
        float4 t = H4[(size_t)s * 32 + lane];
        acc.x += t.x; acc.y += t.y; acc.z += t.z; acc.w += t.w;
    }
    float dv = dinv[node];
    float4 b = ((const float4*)bias)[lane];
    float4 o;
    o.x = fmaxf(fmaf(acc.x, dv, b.x), 0.f);
    o.y = fmaxf(fmaf(acc.y, dv, b.y), 0.f);
    o.z = fmaxf(fmaf(acc.z, dv, b.z), 0.f);
    o.w = fmaxf(fmaf(acc.w, dv, b.w), 0.f);
    ((float4*)out)[(size_t)node * 32 + lane] = o;
}

// ---------------- mean pool (batch sorted -> contiguous ranges) ----------------

__global__ __launch_bounds__(128) void pool_k(const float* __restrict__ h, const int* __restrict__ gstart,
                                              const int* __restrict__ gcnt, float* __restrict__ pooled) {
    int g = blockIdx.x;
    int t = threadIdx.x;
    int beg = gstart[g], c = gcnt[g];
    float s = 0.f;
    for (int i = 0; i < c; ++i) s += h[(size_t)(beg + i) * CH + t];
    float inv = 1.0f / fmaxf((float)c, 1.0f);
    pooled[(size_t)g * CH + t] = s * inv;
}

// ---------------- FC + sigmoid: [512x128]@[128x16] ----------------

__global__ __launch_bounds__(256) void fc_k(const float* __restrict__ pooled, const float* __restrict__ Wfc,
                                            const float* __restrict__ bfc, float* __restrict__ out) {
    __shared__ float ws[CH * OCH];
    for (int i = threadIdx.x; i < CH * OCH; i += 256) ws[i] = Wfc[i];
    __syncthreads();
    int tx = threadIdx.x & 15;   // out channel
    int gy = threadIdx.x >> 4;   // 16 graphs per block
    int g = blockIdx.x * 16 + gy;
    float acc = bfc[tx];
    const float* pr = pooled + (size_t)g * CH;
    for (int k = 0; k < CH; ++k) acc = fmaf(pr[k], ws[k * OCH + tx], acc);
    out[(size_t)g * OCH + tx] = 1.0f / (1.0f + expf(-acc));
}

extern "C" void kernel_launch(void* const* d_in, const int* in_sizes, int n_in,
                              void* d_out, int out_size, void* d_ws, size_t ws_size,
                              hipStream_t stream) {
    const float* x    = (const float*)d_in[0];
    const int*   edge = (const int*)d_in[1];
    const int*   batch= (const int*)d_in[2];
    const float* W1   = (const float*)d_in[3];
    const float* b1   = (const float*)d_in[4];
    const float* W2   = (const float*)d_in[5];
    const float* b2   = (const float*)d_in[6];
    const float* Wfc  = (const float*)d_in[7];
    const float* bfc  = (const float*)d_in[8];
    float* out = (float*)d_out;

    const int N = NN;
    const int E = in_sizes[1] / 2;
    const int* src = edge;
    const int* dst = edge + E;

    // workspace layout
    float* h      = (float*)d_ws;             // N*CH
    float* agg    = h + (size_t)N * CH;       // N*CH
    float* dinv   = agg + (size_t)N * CH;     // N
    float* pooled = dinv + N;                 // NG*CH
    int* row_counts = (int*)(pooled + (size_t)NG * CH); // N
    int* row_start  = row_counts + N;         // N+1
    int* cursor     = row_start + N + 1;      // N
    int* csr_src    = cursor + N;             // E
    int* gcnt       = csr_src + E;            // NG
    int* gstart     = gcnt + NG;              // NG+1
    int* part       = gstart + NG + 1;        // scan partials (<=64)

    hipMemsetAsync(row_counts, 0, (size_t)(3 * N + 1) * sizeof(int), stream);
    hipMemsetAsync(gcnt, 0, (size_t)NG * sizeof(int), stream);

    const int tb = 256;
    const int nb = (N + SCHUNK - 1) / SCHUNK;   // 49
    count_dst_k<<<(E + tb - 1) / tb, tb, 0, stream>>>(dst, row_counts, E);
    scanA_k<<<nb, 256, 0, stream>>>(row_counts, part, N);
    scanB_k<<<1, 1024, 0, stream>>>(part, nb, row_start, N);
    scanC_k<<<nb, 256, 0, stream>>>(row_counts, part, row_start, N);
    dinv_k<<<(N + tb - 1) / tb, tb, 0, stream>>>(row_counts, dinv, N);
    fill_csr_k<<<(E + tb - 1) / tb, tb, 0, stream>>>(src, dst, row_start, cursor, csr_src, E);
    hist_batch_k<<<(N + tb - 1) / tb, tb, 0, stream>>>(batch, gcnt, N);
    scan_gr_k<<<1, 512, 0, stream>>>(gcnt, gstart);

    gemm_scale_k<<<(N + 63) / 64, 256, 0, stream>>>(x, W1, dinv, h, N);
    aggregate_k<<<(N + 7) / 8, 256, 0, stream>>>(h, dinv, row_start, csr_src, b1, agg, N);
    gemm_scale_k<<<(N + 63) / 64, 256, 0, stream>>>(agg, W2, dinv, h, N);
    aggregate_k<<<(N + 7) / 8, 256, 0, stream>>>(h, dinv, row_start, csr_src, b2, agg, N);
    pool_k<<<NG, 128, 0, stream>>>(agg, gstart, gcnt, pooled);
    fc_k<<<NG / 16, 256, 0, stream>>>(pooled, Wfc, bfc, out);
}

// Round 3
// 280.203 us; speedup vs baseline: 1.3902x; 1.1560x over previous
//
#include <hip/hip_runtime.h>
#include <hip/hip_fp16.h>
#include <math.h>

#define NN 50000
#define CH 128
#define NG 512
#define OCH 16
#define SCHUNK 1024

// ---------------- CSR build ----------------

// fused: edge-dst histogram (i<e) + batch histogram (i<n)
__global__ void count_dst_k(const int* __restrict__ dst, int* __restrict__ cnt, int e,
                            const int* __restrict__ batch, int* __restrict__ gcnt, int n) {
    int i = blockIdx.x * blockDim.x + threadIdx.x;
    if (i < e) atomicAdd(&cnt[dst[i]], 1);
    if (i < n) atomicAdd(&gcnt[batch[i]], 1);
}

// ---- 3-phase device-wide exclusive scan of n ints ----
__global__ __launch_bounds__(256) void scanA_k(const int* __restrict__ cnt, int* __restrict__ part, int n) {
    __shared__ int s[256];
    int base = blockIdx.x * SCHUNK;
    int t = threadIdx.x;
    int sum = 0;
#pragma unroll
    for (int j = 0; j < 4; ++j) {
        int idx = base + t * 4 + j;
        if (idx < n) sum += cnt[idx];
    }
    s[t] = sum;
    __syncthreads();
    for (int off = 128; off > 0; off >>= 1) {
        if (t < off) s[t] += s[t + off];
        __syncthreads();
    }
    if (t == 0) part[blockIdx.x] = s[0];
}

// fused: scan of block partials (nb entries) + exclusive scan of 512 graph counts
__global__ __launch_bounds__(1024) void scanB_k(int* __restrict__ part, int nb, int* __restrict__ row_start, int n,
                                                const int* __restrict__ gcnt, int* __restrict__ gstart) {
    __shared__ int s[1024];
    int t = threadIdx.x;
    int v = (t < nb) ? part[t] : 0;
    s[t] = v;
    __syncthreads();
    for (int off = 1; off < 1024; off <<= 1) {
        int u = (t >= off) ? s[t - off] : 0;
        __syncthreads();
        s[t] += u;
        __syncthreads();
    }
    if (t < nb) part[t] = s[t] - v;            // exclusive scan of partials
    if (t == nb - 1) row_start[n] = s[t];      // grand total
    __syncthreads();
    // phase 2: graph ranges
    int g = (t < NG) ? gcnt[t] : 0;
    s[t] = g;
    __syncthreads();
    for (int off = 1; off < NG; off <<= 1) {
        int u = (t >= off && t < NG) ? s[t - off] : 0;
        __syncthreads();
        if (t < NG) s[t] += u;
        __syncthreads();
    }
    if (t < NG) gstart[t] = s[t] - g;
    if (t == NG - 1) gstart[NG] = s[t];
}

// fused: local scan + add partial, and dinv = rsqrt(deg+1)
__global__ __launch_bounds__(256) void scanC_k(const int* __restrict__ cnt, const int* __restrict__ part,
                                               int* __restrict__ out, float* __restrict__ dinv, int n) {
    __shared__ int s[256];
    int base = blockIdx.x * SCHUNK;
    int t = threadIdx.x;
    int v[4];
    int sum = 0;
#pragma unroll
    for (int j = 0; j < 4; ++j) {
        int idx = base + t * 4 + j;
        v[j] = (idx < n) ? cnt[idx] : 0;
        sum += v[j];
    }
    s[t] = sum;
    __syncthreads();
    for (int off = 1; off < 256; off <<= 1) {
        int u = (t >= off) ? s[t - off] : 0;
        __syncthreads();
        s[t] += u;
        __syncthreads();
    }
    int run = part[blockIdx.x] + s[t] - sum;
#pragma unroll
    for (int j = 0; j < 4; ++j) {
        int idx = base + t * 4 + j;
        if (idx < n) {
            out[idx] = run;
            dinv[idx] = rsqrtf((float)v[j] + 1.0f);
        }
        run += v[j];
    }
}

__global__ void fill_csr_k(const int* __restrict__ src, const int* __restrict__ dst,
                           const int* __restrict__ row_start, int* __restrict__ cursor,
                           int* __restrict__ csr_src, int e) {
    int i = blockIdx.x * blockDim.x + threadIdx.x;
    if (i < e) {
        int d = dst[i];
        int pos = atomicAdd(&cursor[d], 1);
        csr_src[row_start[d] + pos] = src[i];
    }
}

// ---------------- GEMM [n x 128] @ [128 x 128], epilogue scale by dinv[row], fp16 output ----------------

__global__ __launch_bounds__(256) void gemm_scale_k(const float* __restrict__ A, const float* __restrict__ W,
                                                    const float* __restrict__ dinv, __half* __restrict__ C, int n) {
    __shared__ float xs[64][128];
    int rowBase = blockIdx.x * 64;
    const float4* A4 = (const float4*)A;
    for (int i = threadIdx.x; i < 64 * 32; i += 256) {
        int r = i >> 5, c = i & 31;
        int row = rowBase + r;
        float4 v = make_float4(0.f, 0.f, 0.f, 0.f);
        if (row < n) v = A4[(size_t)row * 32 + c];
        ((float4*)xs[r])[c] = v;
    }
    __syncthreads();
    int tx = threadIdx.x & 31;   // col group: cols 4*tx..4*tx+3
    int ty = threadIdx.x >> 5;   // rows ty*8 .. ty*8+7
    float4 acc[8];
#pragma unroll
    for (int r = 0; r < 8; ++r) acc[r] = make_float4(0.f, 0.f, 0.f, 0.f);
    const float4* W4 = (const float4*)W;
    for (int kk = 0; kk < 32; ++kk) {
        float4 xa[8];
#pragma unroll
        for (int r = 0; r < 8; ++r) xa[r] = ((float4*)xs[ty * 8 + r])[kk];
#pragma unroll
        for (int j = 0; j < 4; ++j) {
            float4 w = W4[(size_t)(kk * 4 + j) * 32 + tx];
#pragma unroll
            for (int r = 0; r < 8; ++r) {
                float a = (j == 0) ? xa[r].x : (j == 1) ? xa[r].y : (j == 2) ? xa[r].z : xa[r].w;
                acc[r].x = fmaf(a, w.x, acc[r].x);
                acc[r].y = fmaf(a, w.y, acc[r].y);
                acc[r].z = fmaf(a, w.z, acc[r].z);
                acc[r].w = fmaf(a, w.w, acc[r].w);
            }
        }
    }
#pragma unroll
    for (int r = 0; r < 8; ++r) {
        int row = rowBase + ty * 8 + r;
        if (row < n) {
            float dv = dinv[row];
            __half2 p0 = __floats2half2_rn(acc[r].x * dv, acc[r].y * dv);
            __half2 p1 = __floats2half2_rn(acc[r].z * dv, acc[r].w * dv);
            uint2 pk;
            pk.x = *(const unsigned int*)&p0;
            pk.y = *(const unsigned int*)&p1;
            ((uint2*)C)[(size_t)row * 32 + tx] = pk;   // 8 B per thread, 256 B per row
        }
    }
}

// ---------------- aggregation (fp16 gather): out[v] = relu(dinv[v]*(ht[v] + sum ht[src]) + b) ----------------
// 16 lanes per node, 8 channels/lane via one uint4 (8 halves) load.

__global__ __launch_bounds__(256) void aggregate_h_k(const __half* __restrict__ ht, const float* __restrict__ dinv,
                                                     const int* __restrict__ row_start, const int* __restrict__ csr_src,
                                                     const float* __restrict__ bias, float* __restrict__ out, int n) {
    int node = blockIdx.x * 16 + (threadIdx.x >> 4);
    if (node >= n) return;
    int lane = threadIdx.x & 15;
    const uint4* H = (const uint4*)ht;   // 16 uint4 per row
    float acc[8];
    {
        uint4 v = H[(size_t)node * 16 + lane];   // self contribution
        const __half2* hp = (const __half2*)&v;
#pragma unroll
        for (int j = 0; j < 4; ++j) {
            float2 f = __half22float2(hp[j]);
            acc[2 * j] = f.x; acc[2 * j + 1] = f.y;
        }
    }
    int beg = row_start[node], end = row_start[node + 1];
    for (int i = beg; i < end; ++i) {
        int s = csr_src[i];
        uint4 v = H[(size_t)s * 16 + lane];
        const __half2* hp = (const __half2*)&v;
#pragma unroll
        for (int j = 0; j < 4; ++j) {
            float2 f = __half22float2(hp[j]);
            acc[2 * j] += f.x; acc[2 * j + 1] += f.y;
        }
    }
    float dv = dinv[node];
    float4 b0 = ((const float4*)bias)[2 * lane];
    float4 b1 = ((const float4*)bias)[2 * lane + 1];
    float4 o0, o1;
    o0.x = fmaxf(fmaf(acc[0], dv, b0.x), 0.f);
    o0.y = fmaxf(fmaf(acc[1], dv, b0.y), 0.f);
    o0.z = fmaxf(fmaf(acc[2], dv, b0.z), 0.f);
    o0.w = fmaxf(fmaf(acc[3], dv, b0.w), 0.f);
    o1.x = fmaxf(fmaf(acc[4], dv, b1.x), 0.f);
    o1.y = fmaxf(fmaf(acc[5], dv, b1.y), 0.f);
    o1.z = fmaxf(fmaf(acc[6], dv, b1.z), 0.f);
    o1.w = fmaxf(fmaf(acc[7], dv, b1.w), 0.f);
    ((float4*)out)[(size_t)node * 32 + 2 * lane] = o0;
    ((float4*)out)[(size_t)node * 32 + 2 * lane + 1] = o1;
}

// ---------------- mean pool (batch sorted -> contiguous ranges) ----------------

__global__ __launch_bounds__(128) void pool_k(const float* __restrict__ h, const int* __restrict__ gstart,
                                              const int* __restrict__ gcnt, float* __restrict__ pooled) {
    int g = blockIdx.x;
    int t = threadIdx.x;
    int beg = gstart[g], c = gcnt[g];
    float s = 0.f;
    for (int i = 0; i < c; ++i) s += h[(size_t)(beg + i) * CH + t];
    float inv = 1.0f / fmaxf((float)c, 1.0f);
    pooled[(size_t)g * CH + t] = s * inv;
}

// ---------------- FC + sigmoid: [512x128]@[128x16] ----------------

__global__ __launch_bounds__(256) void fc_k(const float* __restrict__ pooled, const float* __restrict__ Wfc,
                                            const float* __restrict__ bfc, float* __restrict__ out) {
    __shared__ float ws[CH * OCH];
    for (int i = threadIdx.x; i < CH * OCH; i += 256) ws[i] = Wfc[i];
    __syncthreads();
    int tx = threadIdx.x & 15;   // out channel
    int gy = threadIdx.x >> 4;   // 16 graphs per block
    int g = blockIdx.x * 16 + gy;
    float acc = bfc[tx];
    const float* pr = pooled + (size_t)g * CH;
    for (int k = 0; k < CH; ++k) acc = fmaf(pr[k], ws[k * OCH + tx], acc);
    out[(size_t)g * OCH + tx] = 1.0f / (1.0f + expf(-acc));
}

extern "C" void kernel_launch(void* const* d_in, const int* in_sizes, int n_in,
                              void* d_out, int out_size, void* d_ws, size_t ws_size,
                              hipStream_t stream) {
    const float* x    = (const float*)d_in[0];
    const int*   edge = (const int*)d_in[1];
    const int*   batch= (const int*)d_in[2];
    const float* W1   = (const float*)d_in[3];
    const float* b1   = (const float*)d_in[4];
    const float* W2   = (const float*)d_in[5];
    const float* b2   = (const float*)d_in[6];
    const float* Wfc  = (const float*)d_in[7];
    const float* bfc  = (const float*)d_in[8];
    float* out = (float*)d_out;

    const int N = NN;
    const int E = in_sizes[1] / 2;
    const int* src = edge;
    const int* dst = edge + E;

    // workspace layout (h region holds halves but reserved as floats)
    float* hf     = (float*)d_ws;             // N*CH floats reserved; used as __half[N*CH]
    float* agg    = hf + (size_t)N * CH;      // N*CH
    float* dinv   = agg + (size_t)N * CH;     // N
    float* pooled = dinv + N;                 // NG*CH
    int* row_counts = (int*)(pooled + (size_t)NG * CH); // N
    int* row_start  = row_counts + N;         // N+1
    int* cursor     = row_start + N + 1;      // N
    int* csr_src    = cursor + N;             // E
    int* gcnt       = csr_src + E;            // NG
    int* gstart     = gcnt + NG;              // NG+1
    int* part       = gstart + NG + 1;        // scan partials (<=64)
    __half* h = (__half*)hf;

    hipMemsetAsync(row_counts, 0, (size_t)(3 * N + 1) * sizeof(int), stream);
    hipMemsetAsync(gcnt, 0, (size_t)NG * sizeof(int), stream);

    const int tb = 256;
    const int nb = (N + SCHUNK - 1) / SCHUNK;   // 49
    count_dst_k<<<(E + tb - 1) / tb, tb, 0, stream>>>(dst, row_counts, E, batch, gcnt, N);
    scanA_k<<<nb, 256, 0, stream>>>(row_counts, part, N);
    scanB_k<<<1, 1024, 0, stream>>>(part, nb, row_start, N, gcnt, gstart);
    scanC_k<<<nb, 256, 0, stream>>>(row_counts, part, row_start, dinv, N);
    fill_csr_k<<<(E + tb - 1) / tb, tb, 0, stream>>>(src, dst, row_start, cursor, csr_src, E);

    gemm_scale_k<<<(N + 63) / 64, 256, 0, stream>>>(x, W1, dinv, h, N);
    aggregate_h_k<<<(N + 15) / 16, 256, 0, stream>>>(h, dinv, row_start, csr_src, b1, agg, N);
    gemm_scale_k<<<(N + 63) / 64, 256, 0, stream>>>(agg, W2, dinv, h, N);
    aggregate_h_k<<<(N + 15) / 16, 256, 0, stream>>>(h, dinv, row_start, csr_src, b2, agg, N);
    pool_k<<<NG, 128, 0, stream>>>(agg, gstart, gcnt, pooled);
    fc_k<<<NG / 16, 256, 0, stream>>>(pooled, Wfc, bfc, out);
}

// Round 4
// 216.658 us; speedup vs baseline: 1.7979x; 1.2933x over previous
//
#include <hip/hip_runtime.h>
#include <hip/hip_fp16.h>
#include <math.h>

#define NN 50000
#define CH 128
#define NG 512
#define OCH 16
#define CAP 64   // bucket capacity per node; deg ~ Poisson(12), P(>=64) ~ 1e-30

// ---------------- bucket-CSR build: one atomic pass ----------------

__global__ void fill_bucket_k(const int* __restrict__ src, const int* __restrict__ dst,
                              int* __restrict__ cursor, int* __restrict__ csr, int e) {
    int i = blockIdx.x * blockDim.x + threadIdx.x;
    if (i < e) {
        int d = dst[i];
        int pos = atomicAdd(&cursor[d], 1);
        if (pos < CAP) csr[d * CAP + pos] = src[i];
    }
}

__global__ void dinv_k(const int* __restrict__ cursor, float* __restrict__ dinv, int n) {
    int i = blockIdx.x * blockDim.x + threadIdx.x;
    if (i < n) dinv[i] = rsqrtf((float)cursor[i] + 1.0f);   // +1 self-loop
}

// batch is sorted: gstart[g] = lower_bound(batch, g), g in [0, NG]
__global__ void gstart_k(const int* __restrict__ batch, int n, int* __restrict__ gstart) {
    int g = blockIdx.x * blockDim.x + threadIdx.x;
    if (g > NG) return;
    int lo = 0, hi = n;
    while (lo < hi) {
        int mid = (lo + hi) >> 1;
        if (batch[mid] < g) lo = mid + 1; else hi = mid;
    }
    gstart[g] = lo;
}

// ---------------- GEMM [n x 128] @ [128 x 128], epilogue scale by dinv[row], fp16 out ----------------

template <typename AT>
__global__ __launch_bounds__(256) void gemm_scale_k(const AT* __restrict__ A, const float* __restrict__ W,
                                                    const float* __restrict__ dinv, __half* __restrict__ C, int n) {
    __shared__ float xs[64][128];
    int rowBase = blockIdx.x * 64;
    if constexpr (sizeof(AT) == 4) {
        const float4* A4 = (const float4*)A;
        for (int i = threadIdx.x; i < 64 * 32; i += 256) {
            int r = i >> 5, c = i & 31;
            int row = rowBase + r;
            float4 v = make_float4(0.f, 0.f, 0.f, 0.f);
            if (row < n) v = A4[(size_t)row * 32 + c];
            ((float4*)xs[r])[c] = v;
        }
    } else {
        const uint4* A16 = (const uint4*)A;   // 16 uint4 (8 halves each) per row
        for (int i = threadIdx.x; i < 64 * 16; i += 256) {
            int r = i >> 4, c = i & 15;
            int row = rowBase + r;
            uint4 v = make_uint4(0, 0, 0, 0);
            if (row < n) v = A16[(size_t)row * 16 + c];
            const __half2* hp = (const __half2*)&v;
            float4 f0, f1;
            float2 a = __half22float2(hp[0]), b = __half22float2(hp[1]);
            float2 cc = __half22float2(hp[2]), d = __half22float2(hp[3]);
            f0.x = a.x; f0.y = a.y; f0.z = b.x; f0.w = b.y;
            f1.x = cc.x; f1.y = cc.y; f1.z = d.x; f1.w = d.y;
            ((float4*)&xs[r][c * 8])[0] = f0;
            ((float4*)&xs[r][c * 8])[1] = f1;
        }
    }
    __syncthreads();
    int tx = threadIdx.x & 31;   // cols 4*tx..4*tx+3
    int ty = threadIdx.x >> 5;   // rows ty*8 .. ty*8+7
    float4 acc[8];
#pragma unroll
    for (int r = 0; r < 8; ++r) acc[r] = make_float4(0.f, 0.f, 0.f, 0.f);
    const float4* W4 = (const float4*)W;
    for (int kk = 0; kk < 32; ++kk) {
        float4 xa[8];
#pragma unroll
        for (int r = 0; r < 8; ++r) xa[r] = ((float4*)xs[ty * 8 + r])[kk];
#pragma unroll
        for (int j = 0; j < 4; ++j) {
            float4 w = W4[(size_t)(kk * 4 + j) * 32 + tx];
#pragma unroll
            for (int r = 0; r < 8; ++r) {
                float a = (j == 0) ? xa[r].x : (j == 1) ? xa[r].y : (j == 2) ? xa[r].z : xa[r].w;
                acc[r].x = fmaf(a, w.x, acc[r].x);
                acc[r].y = fmaf(a, w.y, acc[r].y);
                acc[r].z = fmaf(a, w.z, acc[r].z);
                acc[r].w = fmaf(a, w.w, acc[r].w);
            }
        }
    }
#pragma unroll
    for (int r = 0; r < 8; ++r) {
        int row = rowBase + ty * 8 + r;
        if (row < n) {
            float dv = dinv[row];
            __half2 p0 = __floats2half2_rn(acc[r].x * dv, acc[r].y * dv);
            __half2 p1 = __floats2half2_rn(acc[r].z * dv, acc[r].w * dv);
            uint2 pk;
            pk.x = *(const unsigned int*)&p0;
            pk.y = *(const unsigned int*)&p1;
            ((uint2*)C)[(size_t)row * 32 + tx] = pk;
        }
    }
}

// ---------------- aggregation (fp16 gather, bucket rows): relu(dinv[v]*(ht[v]+sum ht[src])+b) -> fp16 ----------------

__global__ __launch_bounds__(256) void aggregate_h_k(const __half* __restrict__ ht, const float* __restrict__ dinv,
                                                     const int* __restrict__ cursor, const int* __restrict__ csr,
                                                     const float* __restrict__ bias, __half* __restrict__ out, int n) {
    int node = blockIdx.x * 16 + (threadIdx.x >> 4);
    if (node >= n) return;
    int lane = threadIdx.x & 15;
    const uint4* H = (const uint4*)ht;   // 16 uint4 per row
    float acc[8];
    {
        uint4 v = H[(size_t)node * 16 + lane];   // self contribution
        const __half2* hp = (const __half2*)&v;
#pragma unroll
        for (int j = 0; j < 4; ++j) {
            float2 f = __half22float2(hp[j]);
            acc[2 * j] = f.x; acc[2 * j + 1] = f.y;
        }
    }
    int deg = cursor[node];
    if (deg > CAP) deg = CAP;
    const int* row = csr + (size_t)node * CAP;
    for (int i = 0; i < deg; ++i) {
        int s = row[i];
        uint4 v = H[(size_t)s * 16 + lane];
        const __half2* hp = (const __half2*)&v;
#pragma unroll
        for (int j = 0; j < 4; ++j) {
            float2 f = __half22float2(hp[j]);
            acc[2 * j] += f.x; acc[2 * j + 1] += f.y;
        }
    }
    float dv = dinv[node];
    float4 b0 = ((const float4*)bias)[2 * lane];
    float4 b1 = ((const float4*)bias)[2 * lane + 1];
    float r0 = fmaxf(fmaf(acc[0], dv, b0.x), 0.f);
    float r1 = fmaxf(fmaf(acc[1], dv, b0.y), 0.f);
    float r2 = fmaxf(fmaf(acc[2], dv, b0.z), 0.f);
    float r3 = fmaxf(fmaf(acc[3], dv, b0.w), 0.f);
    float r4 = fmaxf(fmaf(acc[4], dv, b1.x), 0.f);
    float r5 = fmaxf(fmaf(acc[5], dv, b1.y), 0.f);
    float r6 = fmaxf(fmaf(acc[6], dv, b1.z), 0.f);
    float r7 = fmaxf(fmaf(acc[7], dv, b1.w), 0.f);
    __half2 q0 = __floats2half2_rn(r0, r1);
    __half2 q1 = __floats2half2_rn(r2, r3);
    __half2 q2 = __floats2half2_rn(r4, r5);
    __half2 q3 = __floats2half2_rn(r6, r7);
    uint4 pk;
    pk.x = *(const unsigned int*)&q0;
    pk.y = *(const unsigned int*)&q1;
    pk.z = *(const unsigned int*)&q2;
    pk.w = *(const unsigned int*)&q3;
    ((uint4*)out)[(size_t)node * 16 + lane] = pk;
}

// ---------------- mean pool (fp16 in, fp32 out) ----------------

__global__ __launch_bounds__(128) void pool_k(const __half* __restrict__ h, const int* __restrict__ gstart,
                                              float* __restrict__ pooled) {
    int g = blockIdx.x;
    int t = threadIdx.x;
    int beg = gstart[g], end = gstart[g + 1];
    int c = end - beg;
    float s = 0.f;
    for (int i = 0; i < c; ++i) s += __half2float(h[(size_t)(beg + i) * CH + t]);
    float inv = 1.0f / fmaxf((float)c, 1.0f);
    pooled[(size_t)g * CH + t] = s * inv;
}

// ---------------- FC + sigmoid: [512x128]@[128x16] ----------------

__global__ __launch_bounds__(256) void fc_k(const float* __restrict__ pooled, const float* __restrict__ Wfc,
                                            const float* __restrict__ bfc, float* __restrict__ out) {
    __shared__ float ws[CH * OCH];
    for (int i = threadIdx.x; i < CH * OCH; i += 256) ws[i] = Wfc[i];
    __syncthreads();
    int tx = threadIdx.x & 15;   // out channel
    int gy = threadIdx.x >> 4;   // 16 graphs per block
    int g = blockIdx.x * 16 + gy;
    float acc = bfc[tx];
    const float* pr = pooled + (size_t)g * CH;
    for (int k = 0; k < CH; ++k) acc = fmaf(pr[k], ws[k * OCH + tx], acc);
    out[(size_t)g * OCH + tx] = 1.0f / (1.0f + expf(-acc));
}

extern "C" void kernel_launch(void* const* d_in, const int* in_sizes, int n_in,
                              void* d_out, int out_size, void* d_ws, size_t ws_size,
                              hipStream_t stream) {
    const float* x    = (const float*)d_in[0];
    const int*   edge = (const int*)d_in[1];
    const int*   batch= (const int*)d_in[2];
    const float* W1   = (const float*)d_in[3];
    const float* b1   = (const float*)d_in[4];
    const float* W2   = (const float*)d_in[5];
    const float* b2   = (const float*)d_in[6];
    const float* Wfc  = (const float*)d_in[7];
    const float* bfc  = (const float*)d_in[8];
    float* out = (float*)d_out;

    const int N = NN;
    const int E = in_sizes[1] / 2;
    const int* src = edge;
    const int* dst = edge + E;

    // workspace layout
    __half* h   = (__half*)d_ws;                       // N*CH halves
    __half* agg = h + (size_t)N * CH;                  // N*CH halves
    float* dinv = (float*)(agg + (size_t)N * CH);      // N
    float* pooled = dinv + N;                          // NG*CH
    int* cursor = (int*)(pooled + (size_t)NG * CH);    // N
    int* gstart = cursor + N;                          // NG+1
    int* csr    = gstart + NG + 1;                     // N*CAP

    hipMemsetAsync(cursor, 0, (size_t)N * sizeof(int), stream);

    const int tb = 256;
    fill_bucket_k<<<(E + tb - 1) / tb, tb, 0, stream>>>(src, dst, cursor, csr, E);
    dinv_k<<<(N + tb - 1) / tb, tb, 0, stream>>>(cursor, dinv, N);
    gstart_k<<<3, 256, 0, stream>>>(batch, N, gstart);

    gemm_scale_k<float><<<(N + 63) / 64, 256, 0, stream>>>(x, W1, dinv, h, N);
    aggregate_h_k<<<(N + 15) / 16, 256, 0, stream>>>(h, dinv, cursor, csr, b1, agg, N);
    gemm_scale_k<__half><<<(N + 63) / 64, 256, 0, stream>>>(agg, W2, dinv, h, N);
    aggregate_h_k<<<(N + 15) / 16, 256, 0, stream>>>(h, dinv, cursor, csr, b2, agg, N);
    pool_k<<<NG, 128, 0, stream>>>(agg, gstart, pooled);
    fc_k<<<NG / 16, 256, 0, stream>>>(pooled, Wfc, bfc, out);
}

// Round 5
// 207.706 us; speedup vs baseline: 1.8754x; 1.0431x over previous
//
#include <hip/hip_runtime.h>
#include <hip/hip_fp16.h>
#include <math.h>

#define NN 50000
#define CH 128
#define NG 512
#define OCH 16
#define CAP 64   // bucket capacity per node; deg ~ Poisson(12), P(>=64) ~ 1e-30

// ---------------- fused init: zero cursor + gstart via binary search on sorted batch ----------------

__global__ void init_k(int* __restrict__ cursor, const int* __restrict__ batch, int n,
                       int* __restrict__ gstart) {
    int i = blockIdx.x * blockDim.x + threadIdx.x;
    if (i < n) cursor[i] = 0;
    if (i <= NG) {
        int lo = 0, hi = n;
        while (lo < hi) {
            int mid = (lo + hi) >> 1;
            if (batch[mid] < i) lo = mid + 1; else hi = mid;
        }
        gstart[i] = lo;
    }
}

// ---------------- bucket-CSR build: one atomic pass ----------------

__global__ void fill_bucket_k(const int* __restrict__ src, const int* __restrict__ dst,
                              int* __restrict__ cursor, int* __restrict__ csr, int e) {
    int i = blockIdx.x * blockDim.x + threadIdx.x;
    if (i < e) {
        int d = dst[i];
        int pos = atomicAdd(&cursor[d], 1);
        if (pos < CAP) csr[d * CAP + pos] = src[i];
    }
}

// ---------------- GEMM [n x 128] @ [128 x 128], epilogue scale by rsqrt(deg+1), fp16 out ----------------

template <typename AT>
__global__ __launch_bounds__(256) void gemm_scale_k(const AT* __restrict__ A, const float* __restrict__ W,
                                                    const int* __restrict__ cursor, __half* __restrict__ C, int n) {
    __shared__ float xs[64][128];
    int rowBase = blockIdx.x * 64;
    if constexpr (sizeof(AT) == 4) {
        const float4* A4 = (const float4*)A;
        for (int i = threadIdx.x; i < 64 * 32; i += 256) {
            int r = i >> 5, c = i & 31;
            int row = rowBase + r;
            float4 v = make_float4(0.f, 0.f, 0.f, 0.f);
            if (row < n) v = A4[(size_t)row * 32 + c];
            ((float4*)xs[r])[c] = v;
        }
    } else {
        const uint4* A16 = (const uint4*)A;   // 16 uint4 (8 halves each) per row
        for (int i = threadIdx.x; i < 64 * 16; i += 256) {
            int r = i >> 4, c = i & 15;
            int row = rowBase + r;
            uint4 v = make_uint4(0, 0, 0, 0);
            if (row < n) v = A16[(size_t)row * 16 + c];
            const __half2* hp = (const __half2*)&v;
            float4 f0, f1;
            float2 a = __half22float2(hp[0]), b = __half22float2(hp[1]);
            float2 cc = __half22float2(hp[2]), d = __half22float2(hp[3]);
            f0.x = a.x; f0.y = a.y; f0.z = b.x; f0.w = b.y;
            f1.x = cc.x; f1.y = cc.y; f1.z = d.x; f1.w = d.y;
            ((float4*)&xs[r][c * 8])[0] = f0;
            ((float4*)&xs[r][c * 8])[1] = f1;
        }
    }
    __syncthreads();
    int tx = threadIdx.x & 31;   // cols 4*tx..4*tx+3
    int ty = threadIdx.x >> 5;   // rows ty*8 .. ty*8+7
    float4 acc[8];
#pragma unroll
    for (int r = 0; r < 8; ++r) acc[r] = make_float4(0.f, 0.f, 0.f, 0.f);
    const float4* W4 = (const float4*)W;
    for (int kk = 0; kk < 32; ++kk) {
        float4 xa[8];
#pragma unroll
        for (int r = 0; r < 8; ++r) xa[r] = ((float4*)xs[ty * 8 + r])[kk];
#pragma unroll
        for (int j = 0; j < 4; ++j) {
            float4 w = W4[(size_t)(kk * 4 + j) * 32 + tx];
#pragma unroll
            for (int r = 0; r < 8; ++r) {
                float a = (j == 0) ? xa[r].x : (j == 1) ? xa[r].y : (j == 2) ? xa[r].z : xa[r].w;
                acc[r].x = fmaf(a, w.x, acc[r].x);
                acc[r].y = fmaf(a, w.y, acc[r].y);
                acc[r].z = fmaf(a, w.z, acc[r].z);
                acc[r].w = fmaf(a, w.w, acc[r].w);
            }
        }
    }
#pragma unroll
    for (int r = 0; r < 8; ++r) {
        int row = rowBase + ty * 8 + r;
        if (row < n) {
            float dv = rsqrtf((float)cursor[row] + 1.0f);
            __half2 p0 = __floats2half2_rn(acc[r].x * dv, acc[r].y * dv);
            __half2 p1 = __floats2half2_rn(acc[r].z * dv, acc[r].w * dv);
            uint2 pk;
            pk.x = *(const unsigned int*)&p0;
            pk.y = *(const unsigned int*)&p1;
            ((uint2*)C)[(size_t)row * 32 + tx] = pk;
        }
    }
}

// ---------------- aggregation (fp16 gather, bucket rows): relu(dinv*(ht[v]+sum ht[src])+b) -> fp16 ----------------

__global__ __launch_bounds__(256) void aggregate_h_k(const __half* __restrict__ ht,
                                                     const int* __restrict__ cursor, const int* __restrict__ csr,
                                                     const float* __restrict__ bias, __half* __restrict__ out, int n) {
    int node = blockIdx.x * 16 + (threadIdx.x >> 4);
    if (node >= n) return;
    int lane = threadIdx.x & 15;
    const uint4* H = (const uint4*)ht;   // 16 uint4 per row
    float acc[8];
    {
        uint4 v = H[(size_t)node * 16 + lane];   // self contribution
        const __half2* hp = (const __half2*)&v;
#pragma unroll
        for (int j = 0; j < 4; ++j) {
            float2 f = __half22float2(hp[j]);
            acc[2 * j] = f.x; acc[2 * j + 1] = f.y;
        }
    }
    int deg = cursor[node];
    float dv = rsqrtf((float)deg + 1.0f);
    if (deg > CAP) deg = CAP;
    const int* row = csr + (size_t)node * CAP;
    for (int i = 0; i < deg; ++i) {
        int s = row[i];
        uint4 v = H[(size_t)s * 16 + lane];
        const __half2* hp = (const __half2*)&v;
#pragma unroll
        for (int j = 0; j < 4; ++j) {
            float2 f = __half22float2(hp[j]);
            acc[2 * j] += f.x; acc[2 * j + 1] += f.y;
        }
    }
    float4 b0 = ((const float4*)bias)[2 * lane];
    float4 b1 = ((const float4*)bias)[2 * lane + 1];
    float r0 = fmaxf(fmaf(acc[0], dv, b0.x), 0.f);
    float r1 = fmaxf(fmaf(acc[1], dv, b0.y), 0.f);
    float r2 = fmaxf(fmaf(acc[2], dv, b0.z), 0.f);
    float r3 = fmaxf(fmaf(acc[3], dv, b0.w), 0.f);
    float r4 = fmaxf(fmaf(acc[4], dv, b1.x), 0.f);
    float r5 = fmaxf(fmaf(acc[5], dv, b1.y), 0.f);
    float r6 = fmaxf(fmaf(acc[6], dv, b1.z), 0.f);
    float r7 = fmaxf(fmaf(acc[7], dv, b1.w), 0.f);
    __half2 q0 = __floats2half2_rn(r0, r1);
    __half2 q1 = __floats2half2_rn(r2, r3);
    __half2 q2 = __floats2half2_rn(r4, r5);
    __half2 q3 = __floats2half2_rn(r6, r7);
    uint4 pk;
    pk.x = *(const unsigned int*)&q0;
    pk.y = *(const unsigned int*)&q1;
    pk.z = *(const unsigned int*)&q2;
    pk.w = *(const unsigned int*)&q3;
    ((uint4*)out)[(size_t)node * 16 + lane] = pk;
}

// ---------------- fused mean-pool + FC + sigmoid ----------------

__global__ __launch_bounds__(128) void pool_fc_k(const __half* __restrict__ h, const int* __restrict__ gstart,
                                                 const float* __restrict__ Wfc, const float* __restrict__ bfc,
                                                 float* __restrict__ out) {
    __shared__ float ps[CH];
    int g = blockIdx.x;
    int t = threadIdx.x;
    int beg = gstart[g], end = gstart[g + 1];
    int c = end - beg;
    float s = 0.f;
    for (int i = 0; i < c; ++i) s += __half2float(h[(size_t)(beg + i) * CH + t]);
    ps[t] = s / fmaxf((float)c, 1.0f);
    __syncthreads();
    if (t < OCH) {
        float acc = bfc[t];
#pragma unroll 8
        for (int k = 0; k < CH; ++k) acc = fmaf(ps[k], Wfc[k * OCH + t], acc);
        out[(size_t)g * OCH + t] = 1.0f / (1.0f + expf(-acc));
    }
}

extern "C" void kernel_launch(void* const* d_in, const int* in_sizes, int n_in,
                              void* d_out, int out_size, void* d_ws, size_t ws_size,
                              hipStream_t stream) {
    const float* x    = (const float*)d_in[0];
    const int*   edge = (const int*)d_in[1];
    const int*   batch= (const int*)d_in[2];
    const float* W1   = (const float*)d_in[3];
    const float* b1   = (const float*)d_in[4];
    const float* W2   = (const float*)d_in[5];
    const float* b2   = (const float*)d_in[6];
    const float* Wfc  = (const float*)d_in[7];
    const float* bfc  = (const float*)d_in[8];
    float* out = (float*)d_out;

    const int N = NN;
    const int E = in_sizes[1] / 2;
    const int* src = edge;
    const int* dst = edge + E;

    // workspace layout
    __half* h   = (__half*)d_ws;                       // N*CH halves
    __half* agg = h + (size_t)N * CH;                  // N*CH halves
    int* cursor = (int*)(agg + (size_t)N * CH);        // N
    int* gstart = cursor + N;                          // NG+1
    int* csr    = gstart + NG + 1;                     // N*CAP

    const int tb = 256;
    init_k<<<(N + tb - 1) / tb, tb, 0, stream>>>(cursor, batch, N, gstart);
    fill_bucket_k<<<(E + tb - 1) / tb, tb, 0, stream>>>(src, dst, cursor, csr, E);

    gemm_scale_k<float><<<(N + 63) / 64, 256, 0, stream>>>(x, W1, cursor, h, N);
    aggregate_h_k<<<(N + 15) / 16, 256, 0, stream>>>(h, cursor, csr, b1, agg, N);
    gemm_scale_k<__half><<<(N + 63) / 64, 256, 0, stream>>>(agg, W2, cursor, h, N);
    aggregate_h_k<<<(N + 15) / 16, 256, 0, stream>>>(h, cursor, csr, b2, agg, N);
    pool_fc_k<<<NG, 128, 0, stream>>>(agg, gstart, Wfc, bfc, out);
}

// Round 6
// 192.191 us; speedup vs baseline: 2.0268x; 1.0807x over previous
//
#include <hip/hip_runtime.h>
#include <hip/hip_fp16.h>
#include <math.h>

#define NN 50000
#define CH 128
#define NG 512
#define OCH 16
#define CAP 64   // bucket capacity per node; deg ~ Poisson(12), P(>=64) ~ 1e-30

typedef _Float16 half8 __attribute__((ext_vector_type(8)));
typedef float f32x4 __attribute__((ext_vector_type(4)));

// ---------------- fused init: zero cursor + gstart via binary search on sorted batch ----------------

__global__ void init_k(int* __restrict__ cursor, const int* __restrict__ batch, int n,
                       int* __restrict__ gstart) {
    int i = blockIdx.x * blockDim.x + threadIdx.x;
    if (i < n) cursor[i] = 0;
    if (i <= NG) {
        int lo = 0, hi = n;
        while (lo < hi) {
            int mid = (lo + hi) >> 1;
            if (batch[mid] < i) lo = mid + 1; else hi = mid;
        }
        gstart[i] = lo;
    }
}

// ---------------- weight prep: W[k][n] fp32 -> Wt[n][k] fp16 (both layers) ----------------

__global__ __launch_bounds__(256) void prep_k(const float* __restrict__ W1, const float* __restrict__ W2,
                                              _Float16* __restrict__ Wt1, _Float16* __restrict__ Wt2) {
    int i = blockIdx.x * 256 + threadIdx.x;
    if (i < CH * CH) {
        int k = i >> 7, n = i & 127;
        Wt1[n * CH + k] = (_Float16)W1[i];
        Wt2[n * CH + k] = (_Float16)W2[i];
    }
}

// ---------------- bucket-CSR build: one atomic pass, 4 edges/thread ----------------

__global__ void fill_bucket_k(const int* __restrict__ src, const int* __restrict__ dst,
                              int* __restrict__ cursor, int* __restrict__ csr, int e) {
    int i0 = (blockIdx.x * blockDim.x + threadIdx.x) * 4;
    if (i0 + 3 < e) {
        int4 d4 = *(const int4*)&dst[i0];
        int4 s4 = *(const int4*)&src[i0];
        int p0 = atomicAdd(&cursor[d4.x], 1);
        int p1 = atomicAdd(&cursor[d4.y], 1);
        int p2 = atomicAdd(&cursor[d4.z], 1);
        int p3 = atomicAdd(&cursor[d4.w], 1);
        if (p0 < CAP) csr[d4.x * CAP + p0] = s4.x;
        if (p1 < CAP) csr[d4.y * CAP + p1] = s4.y;
        if (p2 < CAP) csr[d4.z * CAP + p2] = s4.z;
        if (p3 < CAP) csr[d4.w * CAP + p3] = s4.w;
    } else {
        for (int j = 0; j < 4; ++j) {
            int i = i0 + j;
            if (i < e) {
                int d = dst[i];
                int pos = atomicAdd(&cursor[d], 1);
                if (pos < CAP) csr[d * CAP + pos] = src[i];
            }
        }
    }
}

// ---------------- MFMA GEMM [n x 128] @ Wt[128][128], epilogue scale rsqrt(deg+1), fp16 out ----------------
// Wave owns 16 rows x 128 cols (8 tiles of 16x16). A from global (cvt if fp32),
// B frags from Wt (32 KB fp16, L1-resident). mfma_f32_16x16x32_f16.
// Layouts (m89-verified family): A: M=lane&15,K=(lane>>4)*8+j; B: N=lane&15,K=same; D: N=lane&15,M=(lane>>4)*4+reg.

template <typename AT>
__global__ __launch_bounds__(256) void gemm_mfma_k(const AT* __restrict__ A, const _Float16* __restrict__ Wt,
                                                   const int* __restrict__ cursor, __half* __restrict__ C, int n) {
    int wave = threadIdx.x >> 6;
    int lane = threadIdx.x & 63;
    int base = blockIdx.x * 64 + wave * 16;
    if (base >= n) return;
    int ma = lane & 15;    // A row / B col within tile
    int kb = lane >> 4;    // k-block 0..3

    f32x4 acc[8];
#pragma unroll
    for (int t = 0; t < 8; ++t) acc[t] = (f32x4){0.f, 0.f, 0.f, 0.f};

#pragma unroll
    for (int kk = 0; kk < 4; ++kk) {
        int k0 = kk * 32 + kb * 8;
        half8 af;
        if constexpr (sizeof(AT) == 4) {
            const float* ap = (const float*)A + (size_t)(base + ma) * CH + k0;
            float4 a0 = ((const float4*)ap)[0];
            float4 a1 = ((const float4*)ap)[1];
            af[0] = (_Float16)a0.x; af[1] = (_Float16)a0.y; af[2] = (_Float16)a0.z; af[3] = (_Float16)a0.w;
            af[4] = (_Float16)a1.x; af[5] = (_Float16)a1.y; af[6] = (_Float16)a1.z; af[7] = (_Float16)a1.w;
        } else {
            af = *(const half8*)((const _Float16*)A + (size_t)(base + ma) * CH + k0);
        }
#pragma unroll
        for (int tn = 0; tn < 8; ++tn) {
            half8 bf = *(const half8*)(Wt + (size_t)(tn * 16 + ma) * CH + k0);
            acc[tn] = __builtin_amdgcn_mfma_f32_16x16x32_f16(af, bf, acc[tn], 0, 0, 0);
        }
    }

    int r0 = base + kb * 4;
    float dv[4];
#pragma unroll
    for (int r = 0; r < 4; ++r) dv[r] = rsqrtf((float)cursor[r0 + r] + 1.0f);
#pragma unroll
    for (int tn = 0; tn < 8; ++tn) {
#pragma unroll
        for (int r = 0; r < 4; ++r) {
            C[(size_t)(r0 + r) * CH + tn * 16 + ma] = __float2half(acc[tn][r] * dv[r]);
        }
    }
}

// ---------------- aggregation (fp16 gather, bucket rows): relu(dinv*(ht[v]+sum ht[src])+b) -> fp16 ----------------

__global__ __launch_bounds__(256) void aggregate_h_k(const __half* __restrict__ ht,
                                                     const int* __restrict__ cursor, const int* __restrict__ csr,
                                                     const float* __restrict__ bias, __half* __restrict__ out, int n) {
    int node = blockIdx.x * 16 + (threadIdx.x >> 4);
    if (node >= n) return;
    int lane = threadIdx.x & 15;
    const uint4* H = (const uint4*)ht;   // 16 uint4 per row
    float acc[8];
    {
        uint4 v = H[(size_t)node * 16 + lane];   // self contribution
        const __half2* hp = (const __half2*)&v;
#pragma unroll
        for (int j = 0; j < 4; ++j) {
            float2 f = __half22float2(hp[j]);
            acc[2 * j] = f.x; acc[2 * j + 1] = f.y;
        }
    }
    int deg = cursor[node];
    float dv = rsqrtf((float)deg + 1.0f);
    if (deg > CAP) deg = CAP;
    const int* row = csr + (size_t)node * CAP;
    for (int i = 0; i < deg; ++i) {
        int s = row[i];
        uint4 v = H[(size_t)s * 16 + lane];
        const __half2* hp = (const __half2*)&v;
#pragma unroll
        for (int j = 0; j < 4; ++j) {
            float2 f = __half22float2(hp[j]);
            acc[2 * j] += f.x; acc[2 * j + 1] += f.y;
        }
    }
    float4 b0 = ((const float4*)bias)[2 * lane];
    float4 b1 = ((const float4*)bias)[2 * lane + 1];
    float r0 = fmaxf(fmaf(acc[0], dv, b0.x), 0.f);
    float r1 = fmaxf(fmaf(acc[1], dv, b0.y), 0.f);
    float r2 = fmaxf(fmaf(acc[2], dv, b0.z), 0.f);
    float r3 = fmaxf(fmaf(acc[3], dv, b0.w), 0.f);
    float r4 = fmaxf(fmaf(acc[4], dv, b1.x), 0.f);
    float r5 = fmaxf(fmaf(acc[5], dv, b1.y), 0.f);
    float r6 = fmaxf(fmaf(acc[6], dv, b1.z), 0.f);
    float r7 = fmaxf(fmaf(acc[7], dv, b1.w), 0.f);
    __half2 q0 = __floats2half2_rn(r0, r1);
    __half2 q1 = __floats2half2_rn(r2, r3);
    __half2 q2 = __floats2half2_rn(r4, r5);
    __half2 q3 = __floats2half2_rn(r6, r7);
    uint4 pk;
    pk.x = *(const unsigned int*)&q0;
    pk.y = *(const unsigned int*)&q1;
    pk.z = *(const unsigned int*)&q2;
    pk.w = *(const unsigned int*)&q3;
    ((uint4*)out)[(size_t)node * 16 + lane] = pk;
}

// ---------------- fused mean-pool + FC + sigmoid ----------------

__global__ __launch_bounds__(128) void pool_fc_k(const __half* __restrict__ h, const int* __restrict__ gstart,
                                                 const float* __restrict__ Wfc, const float* __restrict__ bfc,
                                                 float* __restrict__ out) {
    __shared__ float ps[CH];
    int g = blockIdx.x;
    int t = threadIdx.x;
    int beg = gstart[g], end = gstart[g + 1];
    int c = end - beg;
    float s = 0.f;
    for (int i = 0; i < c; ++i) s += __half2float(h[(size_t)(beg + i) * CH + t]);
    ps[t] = s / fmaxf((float)c, 1.0f);
    __syncthreads();
    if (t < OCH) {
        float acc = bfc[t];
#pragma unroll 8
        for (int k = 0; k < CH; ++k) acc = fmaf(ps[k], Wfc[k * OCH + t], acc);
        out[(size_t)g * OCH + t] = 1.0f / (1.0f + expf(-acc));
    }
}

extern "C" void kernel_launch(void* const* d_in, const int* in_sizes, int n_in,
                              void* d_out, int out_size, void* d_ws, size_t ws_size,
                              hipStream_t stream) {
    const float* x    = (const float*)d_in[0];
    const int*   edge = (const int*)d_in[1];
    const int*   batch= (const int*)d_in[2];
    const float* W1   = (const float*)d_in[3];
    const float* b1   = (const float*)d_in[4];
    const float* W2   = (const float*)d_in[5];
    const float* b2   = (const float*)d_in[6];
    const float* Wfc  = (const float*)d_in[7];
    const float* bfc  = (const float*)d_in[8];
    float* out = (float*)d_out;

    const int N = NN;
    const int E = in_sizes[1] / 2;
    const int* src = edge;
    const int* dst = edge + E;

    // workspace layout (16B alignment preserved in order)
    __half* h     = (__half*)d_ws;                     // N*CH halves
    __half* agg   = h + (size_t)N * CH;                // N*CH halves
    _Float16* Wt1 = (_Float16*)(agg + (size_t)N * CH); // CH*CH halves
    _Float16* Wt2 = Wt1 + CH * CH;                     // CH*CH halves
    int* cursor   = (int*)(Wt2 + CH * CH);             // N
    int* gstart   = cursor + N;                        // NG+1
    int* csr      = gstart + NG + 1;                   // N*CAP

    const int tb = 256;
    init_k<<<(N + tb - 1) / tb, tb, 0, stream>>>(cursor, batch, N, gstart);
    prep_k<<<(CH * CH + 255) / 256, 256, 0, stream>>>(W1, W2, Wt1, Wt2);
    fill_bucket_k<<<(E / 4 + tb - 1) / tb, tb, 0, stream>>>(src, dst, cursor, csr, E);

    gemm_mfma_k<float><<<(N + 63) / 64, 256, 0, stream>>>(x, Wt1, cursor, h, N);
    aggregate_h_k<<<(N + 15) / 16, 256, 0, stream>>>(h, cursor, csr, b1, agg, N);
    gemm_mfma_k<__half><<<(N + 63) / 64, 256, 0, stream>>>(agg, Wt2, cursor, h, N);
    aggregate_h_k<<<(N + 15) / 16, 256, 0, stream>>>(h, cursor, csr, b2, agg, N);
    pool_fc_k<<<NG, 128, 0, stream>>>(agg, gstart, Wfc, bfc, out);
}

// Round 7
// 175.872 us; speedup vs baseline: 2.2149x; 1.0928x over previous
//
#include <hip/hip_runtime.h>
#include <hip/hip_fp16.h>
#include <math.h>

#define NN 50000
#define CH 128
#define NG 512
#define OCH 16
#define CAP 64   // bucket capacity per node; deg ~ Poisson(12), P(>=64) ~ 1e-30

typedef _Float16 half8 __attribute__((ext_vector_type(8)));
typedef float f32x4 __attribute__((ext_vector_type(4)));

// ---------------- fused init: zero cursor + gstart binsearch + weight transpose/cvt ----------------

__global__ void init_prep_k(int* __restrict__ cursor, const int* __restrict__ batch, int n,
                            int* __restrict__ gstart,
                            const float* __restrict__ W1, const float* __restrict__ W2,
                            _Float16* __restrict__ Wt1, _Float16* __restrict__ Wt2) {
    int i = blockIdx.x * blockDim.x + threadIdx.x;
    if (i < n) cursor[i] = 0;
    if (i <= NG) {
        int lo = 0, hi = n;
        while (lo < hi) {
            int mid = (lo + hi) >> 1;
            if (batch[mid] < i) lo = mid + 1; else hi = mid;
        }
        gstart[i] = lo;
    }
    if (i < CH * CH) {
        int k = i >> 7, c = i & 127;
        Wt1[c * CH + k] = (_Float16)W1[i];
        Wt2[c * CH + k] = (_Float16)W2[i];
    }
}

// ---------------- MFMA GEMM body: [n x 128] @ Wt[128][128] -> fp16, optional rsqrt(deg+1) row scale ----------------
// Wave owns 16 rows x 128 cols. A from global (cvt if fp32), B frags from Wt (32 KB, L1-resident).
// Layouts: A: M=lane&15,K=(lane>>4)*8+j; B: N=lane&15,K=same; D: N=lane&15,M=(lane>>4)*4+reg.

template <typename AT, bool SCALE>
__device__ __forceinline__ void gemm_body(const AT* __restrict__ A, const _Float16* __restrict__ Wt,
                                          const int* __restrict__ cursor, __half* __restrict__ C,
                                          int n, int blk) {
    int wave = threadIdx.x >> 6;
    int lane = threadIdx.x & 63;
    int base = blk * 64 + wave * 16;
    if (base >= n) return;
    int ma = lane & 15;    // A row / B col within tile
    int kb = lane >> 4;    // k-block 0..3

    f32x4 acc[8];
#pragma unroll
    for (int t = 0; t < 8; ++t) acc[t] = (f32x4){0.f, 0.f, 0.f, 0.f};

#pragma unroll
    for (int kk = 0; kk < 4; ++kk) {
        int k0 = kk * 32 + kb * 8;
        half8 af;
        if constexpr (sizeof(AT) == 4) {
            const float* ap = (const float*)A + (size_t)(base + ma) * CH + k0;
            float4 a0 = ((const float4*)ap)[0];
            float4 a1 = ((const float4*)ap)[1];
            af[0] = (_Float16)a0.x; af[1] = (_Float16)a0.y; af[2] = (_Float16)a0.z; af[3] = (_Float16)a0.w;
            af[4] = (_Float16)a1.x; af[5] = (_Float16)a1.y; af[6] = (_Float16)a1.z; af[7] = (_Float16)a1.w;
        } else {
            af = *(const half8*)((const _Float16*)A + (size_t)(base + ma) * CH + k0);
        }
#pragma unroll
        for (int tn = 0; tn < 8; ++tn) {
            half8 bf = *(const half8*)(Wt + (size_t)(tn * 16 + ma) * CH + k0);
            acc[tn] = __builtin_amdgcn_mfma_f32_16x16x32_f16(af, bf, acc[tn], 0, 0, 0);
        }
    }

    int r0 = base + kb * 4;
    float dv[4];
#pragma unroll
    for (int r = 0; r < 4; ++r) dv[r] = SCALE ? rsqrtf((float)cursor[r0 + r] + 1.0f) : 1.0f;
#pragma unroll
    for (int tn = 0; tn < 8; ++tn) {
#pragma unroll
        for (int r = 0; r < 4; ++r) {
            C[(size_t)(r0 + r) * CH + tn * 16 + ma] = __float2half(acc[tn][r] * dv[r]);
        }
    }
}

// ---------------- fused: gemm1 (unscaled) + bucket-CSR build (block-role split) ----------------

__global__ __launch_bounds__(256) void gemm1_fill_k(const float* __restrict__ x, const _Float16* __restrict__ Wt1,
                                                    const int* __restrict__ src, const int* __restrict__ dst,
                                                    int* __restrict__ cursor, int* __restrict__ csr,
                                                    __half* __restrict__ h, int n, int e, int G) {
    if ((int)blockIdx.x < G) {
        gemm_body<float, false>(x, Wt1, nullptr, h, n, blockIdx.x);
    } else {
        int i0 = ((blockIdx.x - G) * 256 + threadIdx.x) * 4;
        if (i0 + 3 < e) {
            int4 d4 = *(const int4*)&dst[i0];
            int4 s4 = *(const int4*)&src[i0];
            int p0 = atomicAdd(&cursor[d4.x], 1);
            int p1 = atomicAdd(&cursor[d4.y], 1);
            int p2 = atomicAdd(&cursor[d4.z], 1);
            int p3 = atomicAdd(&cursor[d4.w], 1);
            if (p0 < CAP) csr[d4.x * CAP + p0] = s4.x;
            if (p1 < CAP) csr[d4.y * CAP + p1] = s4.y;
            if (p2 < CAP) csr[d4.z * CAP + p2] = s4.z;
            if (p3 < CAP) csr[d4.w * CAP + p3] = s4.w;
        } else {
            for (int j = 0; j < 4; ++j) {
                int i = i0 + j;
                if (i < e) {
                    int d = dst[i];
                    int pos = atomicAdd(&cursor[d], 1);
                    if (pos < CAP) csr[d * CAP + pos] = src[i];
                }
            }
        }
    }
}

// ---------------- standalone gemm for layer 2 (A fp16, scaled epilogue) ----------------

__global__ __launch_bounds__(256) void gemm2_k(const _Float16* __restrict__ A, const _Float16* __restrict__ Wt,
                                               const int* __restrict__ cursor, __half* __restrict__ C, int n) {
    gemm_body<_Float16, true>(A, Wt, cursor, C, n, blockIdx.x);
}

// ---------------- aggregation (fp16 gather, bucket rows, int4 index preload) ----------------
// PRESCALED=true  : h rows carry dinv[row] already;   out = relu(dv*(h[v] + sum h[s]) + b)
// PRESCALED=false : h rows raw; per-edge dinv gather; out = relu(dv*(dv*h[v] + sum dinv[s]*h[s]) + b)

template <bool PRESCALED>
__global__ __launch_bounds__(256) void aggregate_k(const __half* __restrict__ ht,
                                                   const int* __restrict__ cursor, const int* __restrict__ csr,
                                                   const float* __restrict__ bias, __half* __restrict__ out, int n) {
    int node = blockIdx.x * 16 + (threadIdx.x >> 4);
    if (node >= n) return;
    int lane = threadIdx.x & 15;
    const uint4* H = (const uint4*)ht;   // 16 uint4 per row
    int deg = cursor[node];
    float dv = rsqrtf((float)deg + 1.0f);
    int degc = deg > CAP ? CAP : deg;

    float acc[8];
    {
        uint4 v = H[(size_t)node * 16 + lane];   // self
        const __half2* hp = (const __half2*)&v;
        float selfs = PRESCALED ? 1.0f : dv;
#pragma unroll
        for (int j = 0; j < 4; ++j) {
            float2 f = __half22float2(hp[j]);
            acc[2 * j] = f.x * selfs; acc[2 * j + 1] = f.y * selfs;
        }
    }

    const int4* row4 = (const int4*)(csr + (size_t)node * CAP);
    int i = 0;
    for (; i + 4 <= degc; i += 4) {
        int4 s4 = row4[i >> 2];
        uint4 v0 = H[(size_t)s4.x * 16 + lane];
        uint4 v1 = H[(size_t)s4.y * 16 + lane];
        uint4 v2 = H[(size_t)s4.z * 16 + lane];
        uint4 v3 = H[(size_t)s4.w * 16 + lane];
        float w0 = 1.f, w1 = 1.f, w2 = 1.f, w3 = 1.f;
        if constexpr (!PRESCALED) {
            w0 = rsqrtf((float)cursor[s4.x] + 1.0f);
            w1 = rsqrtf((float)cursor[s4.y] + 1.0f);
            w2 = rsqrtf((float)cursor[s4.z] + 1.0f);
            w3 = rsqrtf((float)cursor[s4.w] + 1.0f);
        }
        const __half2* p0 = (const __half2*)&v0;
        const __half2* p1 = (const __half2*)&v1;
        const __half2* p2 = (const __half2*)&v2;
        const __half2* p3 = (const __half2*)&v3;
#pragma unroll
        for (int j = 0; j < 4; ++j) {
            float2 f0 = __half22float2(p0[j]);
            float2 f1 = __half22float2(p1[j]);
            float2 f2 = __half22float2(p2[j]);
            float2 f3 = __half22float2(p3[j]);
            acc[2 * j]     = fmaf(f0.x, w0, acc[2 * j]);
            acc[2 * j + 1] = fmaf(f0.y, w0, acc[2 * j + 1]);
            acc[2 * j]     = fmaf(f1.x, w1, acc[2 * j]);
            acc[2 * j + 1] = fmaf(f1.y, w1, acc[2 * j + 1]);
            acc[2 * j]     = fmaf(f2.x, w2, acc[2 * j]);
            acc[2 * j + 1] = fmaf(f2.y, w2, acc[2 * j + 1]);
            acc[2 * j]     = fmaf(f3.x, w3, acc[2 * j]);
            acc[2 * j + 1] = fmaf(f3.y, w3, acc[2 * j + 1]);
        }
    }
    for (; i < degc; ++i) {
        int s = csr[(size_t)node * CAP + i];
        uint4 v = H[(size_t)s * 16 + lane];
        float w = 1.f;
        if constexpr (!PRESCALED) w = rsqrtf((float)cursor[s] + 1.0f);
        const __half2* hp = (const __half2*)&v;
#pragma unroll
        for (int j = 0; j < 4; ++j) {
            float2 f = __half22float2(hp[j]);
            acc[2 * j]     = fmaf(f.x, w, acc[2 * j]);
            acc[2 * j + 1] = fmaf(f.y, w, acc[2 * j + 1]);
        }
    }

    float4 b0 = ((const float4*)bias)[2 * lane];
    float4 b1 = ((const float4*)bias)[2 * lane + 1];
    float r0 = fmaxf(fmaf(acc[0], dv, b0.x), 0.f);
    float r1 = fmaxf(fmaf(acc[1], dv, b0.y), 0.f);
    float r2 = fmaxf(fmaf(acc[2], dv, b0.z), 0.f);
    float r3 = fmaxf(fmaf(acc[3], dv, b0.w), 0.f);
    float r4 = fmaxf(fmaf(acc[4], dv, b1.x), 0.f);
    float r5 = fmaxf(fmaf(acc[5], dv, b1.y), 0.f);
    float r6 = fmaxf(fmaf(acc[6], dv, b1.z), 0.f);
    float r7 = fmaxf(fmaf(acc[7], dv, b1.w), 0.f);
    __half2 q0 = __floats2half2_rn(r0, r1);
    __half2 q1 = __floats2half2_rn(r2, r3);
    __half2 q2 = __floats2half2_rn(r4, r5);
    __half2 q3 = __floats2half2_rn(r6, r7);
    uint4 pk;
    pk.x = *(const unsigned int*)&q0;
    pk.y = *(const unsigned int*)&q1;
    pk.z = *(const unsigned int*)&q2;
    pk.w = *(const unsigned int*)&q3;
    ((uint4*)out)[(size_t)node * 16 + lane] = pk;
}

// ---------------- fused mean-pool + FC + sigmoid ----------------

__global__ __launch_bounds__(128) void pool_fc_k(const __half* __restrict__ h, const int* __restrict__ gstart,
                                                 const float* __restrict__ Wfc, const float* __restrict__ bfc,
                                                 float* __restrict__ out) {
    __shared__ float ps[CH];
    int g = blockIdx.x;
    int t = threadIdx.x;
    int beg = gstart[g], end = gstart[g + 1];
    int c = end - beg;
    float s = 0.f;
    for (int i = 0; i < c; ++i) s += __half2float(h[(size_t)(beg + i) * CH + t]);
    ps[t] = s / fmaxf((float)c, 1.0f);
    __syncthreads();
    if (t < OCH) {
        float acc = bfc[t];
#pragma unroll 8
        for (int k = 0; k < CH; ++k) acc = fmaf(ps[k], Wfc[k * OCH + t], acc);
        out[(size_t)g * OCH + t] = 1.0f / (1.0f + expf(-acc));
    }
}

extern "C" void kernel_launch(void* const* d_in, const int* in_sizes, int n_in,
                              void* d_out, int out_size, void* d_ws, size_t ws_size,
                              hipStream_t stream) {
    const float* x    = (const float*)d_in[0];
    const int*   edge = (const int*)d_in[1];
    const int*   batch= (const int*)d_in[2];
    const float* W1   = (const float*)d_in[3];
    const float* b1   = (const float*)d_in[4];
    const float* W2   = (const float*)d_in[5];
    const float* b2   = (const float*)d_in[6];
    const float* Wfc  = (const float*)d_in[7];
    const float* bfc  = (const float*)d_in[8];
    float* out = (float*)d_out;

    const int N = NN;
    const int E = in_sizes[1] / 2;
    const int* src = edge;
    const int* dst = edge + E;

    // workspace layout (16B alignment preserved in order)
    __half* h     = (__half*)d_ws;                     // N*CH halves
    __half* agg   = h + (size_t)N * CH;                // N*CH halves
    _Float16* Wt1 = (_Float16*)(agg + (size_t)N * CH); // CH*CH halves
    _Float16* Wt2 = Wt1 + CH * CH;                     // CH*CH halves
    int* cursor   = (int*)(Wt2 + CH * CH);             // N
    int* gstart   = cursor + N;                        // NG+1
    int* csr      = gstart + NG + 1;                   // N*CAP

    const int tb = 256;
    const int G = (N + 63) / 64;                 // gemm blocks (782)
    const int F = (E + 1023) / 1024;             // fill blocks (586), 4 edges/thread

    init_prep_k<<<(N + tb - 1) / tb, tb, 0, stream>>>(cursor, batch, N, gstart, W1, W2, Wt1, Wt2);
    gemm1_fill_k<<<G + F, 256, 0, stream>>>(x, Wt1, src, dst, cursor, csr, h, N, E, G);
    aggregate_k<false><<<(N + 15) / 16, 256, 0, stream>>>(h, cursor, csr, b1, agg, N);
    gemm2_k<<<G, 256, 0, stream>>>((const _Float16*)agg, Wt2, cursor, h, N);
    aggregate_k<true><<<(N + 15) / 16, 256, 0, stream>>>(h, cursor, csr, b2, agg, N);
    pool_fc_k<<<NG, 128, 0, stream>>>(agg, gstart, Wfc, bfc, out);
}

// Round 8
// 175.198 us; speedup vs baseline: 2.2234x; 1.0038x over previous
//
#include <hip/hip_runtime.h>
#include <hip/hip_fp16.h>
#include <math.h>

#define NN 50000
#define CH 128
#define NG 512
#define OCH 16
#define CAP 64       // bucket capacity per node; deg ~ Poisson(12), P(>=64) ~ 1e-30
#define CSTRIDE 16   // ints per cursor counter: one 64B line each (anti false-sharing)

typedef _Float16 half8 __attribute__((ext_vector_type(8)));
typedef float f32x4 __attribute__((ext_vector_type(4)));

// ---------------- fused init: zero padded cursor + gstart binsearch + weight transpose/cvt ----------------

__global__ __launch_bounds__(256) void init_prep_k(int* __restrict__ cursor, const int* __restrict__ batch, int n,
                                                   int* __restrict__ gstart,
                                                   const float* __restrict__ W1, const float* __restrict__ W2,
                                                   _Float16* __restrict__ Wt1, _Float16* __restrict__ Wt2) {
    int i = blockIdx.x * blockDim.x + threadIdx.x;
    if (i < n * (CSTRIDE / 4)) ((int4*)cursor)[i] = make_int4(0, 0, 0, 0);   // 200000 int4s
    if (i <= NG) {
        int lo = 0, hi = n;
        while (lo < hi) {
            int mid = (lo + hi) >> 1;
            if (batch[mid] < i) lo = mid + 1; else hi = mid;
        }
        gstart[i] = lo;
    }
    if (i < CH * CH) {
        int k = i >> 7, c = i & 127;
        Wt1[c * CH + k] = (_Float16)W1[i];
        Wt2[c * CH + k] = (_Float16)W2[i];
    }
}

// ---------------- MFMA GEMM body: [n x 128] @ Wt[128][128] -> fp16, optional rsqrt(deg+1) row scale ----------------
// Wave owns 16 rows x 128 cols. A from global (cvt if fp32), B frags from Wt (32 KB, L1-resident).
// Layouts: A: M=lane&15,K=(lane>>4)*8+j; B: N=lane&15,K=same; D: N=lane&15,M=(lane>>4)*4+reg.

template <typename AT, bool SCALE>
__device__ __forceinline__ void gemm_body(const AT* __restrict__ A, const _Float16* __restrict__ Wt,
                                          const int* __restrict__ cursor, __half* __restrict__ C,
                                          int n, int blk) {
    int wave = threadIdx.x >> 6;
    int lane = threadIdx.x & 63;
    int base = blk * 64 + wave * 16;
    if (base >= n) return;
    int ma = lane & 15;    // A row / B col within tile
    int kb = lane >> 4;    // k-block 0..3

    f32x4 acc[8];
#pragma unroll
    for (int t = 0; t < 8; ++t) acc[t] = (f32x4){0.f, 0.f, 0.f, 0.f};

#pragma unroll
    for (int kk = 0; kk < 4; ++kk) {
        int k0 = kk * 32 + kb * 8;
        half8 af;
        if constexpr (sizeof(AT) == 4) {
            const float* ap = (const float*)A + (size_t)(base + ma) * CH + k0;
            float4 a0 = ((const float4*)ap)[0];
            float4 a1 = ((const float4*)ap)[1];
            af[0] = (_Float16)a0.x; af[1] = (_Float16)a0.y; af[2] = (_Float16)a0.z; af[3] = (_Float16)a0.w;
            af[4] = (_Float16)a1.x; af[5] = (_Float16)a1.y; af[6] = (_Float16)a1.z; af[7] = (_Float16)a1.w;
        } else {
            af = *(const half8*)((const _Float16*)A + (size_t)(base + ma) * CH + k0);
        }
#pragma unroll
        for (int tn = 0; tn < 8; ++tn) {
            half8 bf = *(const half8*)(Wt + (size_t)(tn * 16 + ma) * CH + k0);
            acc[tn] = __builtin_amdgcn_mfma_f32_16x16x32_f16(af, bf, acc[tn], 0, 0, 0);
        }
    }

    int r0 = base + kb * 4;
    float dv[4];
#pragma unroll
    for (int r = 0; r < 4; ++r) dv[r] = SCALE ? rsqrtf((float)cursor[(r0 + r) * CSTRIDE] + 1.0f) : 1.0f;
#pragma unroll
    for (int tn = 0; tn < 8; ++tn) {
#pragma unroll
        for (int r = 0; r < 4; ++r) {
            C[(size_t)(r0 + r) * CH + tn * 16 + ma] = __float2half(acc[tn][r] * dv[r]);
        }
    }
}

// ---------------- fused: bucket-CSR build (blocks 0..F) + gemm1 unscaled (blocks F..F+G) ----------------

__global__ __launch_bounds__(256) void gemm1_fill_k(const float* __restrict__ x, const _Float16* __restrict__ Wt1,
                                                    const int* __restrict__ src, const int* __restrict__ dst,
                                                    int* __restrict__ cursor, int* __restrict__ csr,
                                                    __half* __restrict__ h, int n, int e, int F) {
    if ((int)blockIdx.x < F) {
        int i0 = (blockIdx.x * 256 + threadIdx.x) * 4;
        if (i0 + 3 < e) {
            int4 d4 = *(const int4*)&dst[i0];
            int4 s4 = *(const int4*)&src[i0];
            int p0 = atomicAdd(&cursor[d4.x * CSTRIDE], 1);
            int p1 = atomicAdd(&cursor[d4.y * CSTRIDE], 1);
            int p2 = atomicAdd(&cursor[d4.z * CSTRIDE], 1);
            int p3 = atomicAdd(&cursor[d4.w * CSTRIDE], 1);
            if (p0 < CAP) csr[d4.x * CAP + p0] = s4.x;
            if (p1 < CAP) csr[d4.y * CAP + p1] = s4.y;
            if (p2 < CAP) csr[d4.z * CAP + p2] = s4.z;
            if (p3 < CAP) csr[d4.w * CAP + p3] = s4.w;
        } else {
            for (int j = 0; j < 4; ++j) {
                int i = i0 + j;
                if (i < e) {
                    int d = dst[i];
                    int pos = atomicAdd(&cursor[d * CSTRIDE], 1);
                    if (pos < CAP) csr[d * CAP + pos] = src[i];
                }
            }
        }
    } else {
        gemm_body<float, false>(x, Wt1, nullptr, h, n, blockIdx.x - F);
    }
}

// ---------------- standalone gemm for layer 2 (A fp16, scaled epilogue) ----------------

__global__ __launch_bounds__(256) void gemm2_k(const _Float16* __restrict__ A, const _Float16* __restrict__ Wt,
                                               const int* __restrict__ cursor, __half* __restrict__ C, int n) {
    gemm_body<_Float16, true>(A, Wt, cursor, C, n, blockIdx.x);
}

// ---------------- aggregation (fp16 gather, bucket rows, int4 index preload) ----------------
// PRESCALED=true  : h rows carry dinv[row];        out = relu(dv*(h[v] + sum h[s]) + b)
// PRESCALED=false : h raw; per-edge dinv from padded cursor; out = relu(dv*(dv*h[v] + sum dinv[s]*h[s]) + b)

template <bool PRESCALED>
__global__ __launch_bounds__(256) void aggregate_k(const __half* __restrict__ ht,
                                                   const int* __restrict__ cursor, const int* __restrict__ csr,
                                                   const float* __restrict__ bias, __half* __restrict__ out, int n) {
    int node = blockIdx.x * 16 + (threadIdx.x >> 4);
    if (node >= n) return;
    int lane = threadIdx.x & 15;
    const uint4* H = (const uint4*)ht;   // 16 uint4 per row
    int deg = cursor[node * CSTRIDE];
    float dv = rsqrtf((float)deg + 1.0f);
    int degc = deg > CAP ? CAP : deg;

    float acc[8];
    {
        uint4 v = H[(size_t)node * 16 + lane];   // self
        const __half2* hp = (const __half2*)&v;
        float selfs = PRESCALED ? 1.0f : dv;
#pragma unroll
        for (int j = 0; j < 4; ++j) {
            float2 f = __half22float2(hp[j]);
            acc[2 * j] = f.x * selfs; acc[2 * j + 1] = f.y * selfs;
        }
    }

    const int4* row4 = (const int4*)(csr + (size_t)node * CAP);
    int i = 0;
    for (; i + 4 <= degc; i += 4) {
        int4 s4 = row4[i >> 2];
        uint4 v0 = H[(size_t)s4.x * 16 + lane];
        uint4 v1 = H[(size_t)s4.y * 16 + lane];
        uint4 v2 = H[(size_t)s4.z * 16 + lane];
        uint4 v3 = H[(size_t)s4.w * 16 + lane];
        float w0 = 1.f, w1 = 1.f, w2 = 1.f, w3 = 1.f;
        if constexpr (!PRESCALED) {
            w0 = rsqrtf((float)cursor[s4.x * CSTRIDE] + 1.0f);
            w1 = rsqrtf((float)cursor[s4.y * CSTRIDE] + 1.0f);
            w2 = rsqrtf((float)cursor[s4.z * CSTRIDE] + 1.0f);
            w3 = rsqrtf((float)cursor[s4.w * CSTRIDE] + 1.0f);
        }
        const __half2* p0 = (const __half2*)&v0;
        const __half2* p1 = (const __half2*)&v1;
        const __half2* p2 = (const __half2*)&v2;
        const __half2* p3 = (const __half2*)&v3;
#pragma unroll
        for (int j = 0; j < 4; ++j) {
            float2 f0 = __half22float2(p0[j]);
            float2 f1 = __half22float2(p1[j]);
            float2 f2 = __half22float2(p2[j]);
            float2 f3 = __half22float2(p3[j]);
            acc[2 * j]     = fmaf(f0.x, w0, acc[2 * j]);
            acc[2 * j + 1] = fmaf(f0.y, w0, acc[2 * j + 1]);
            acc[2 * j]     = fmaf(f1.x, w1, acc[2 * j]);
            acc[2 * j + 1] = fmaf(f1.y, w1, acc[2 * j + 1]);
            acc[2 * j]     = fmaf(f2.x, w2, acc[2 * j]);
            acc[2 * j + 1] = fmaf(f2.y, w2, acc[2 * j + 1]);
            acc[2 * j]     = fmaf(f3.x, w3, acc[2 * j]);
            acc[2 * j + 1] = fmaf(f3.y, w3, acc[2 * j + 1]);
        }
    }
    for (; i < degc; ++i) {
        int s = csr[(size_t)node * CAP + i];
        uint4 v = H[(size_t)s * 16 + lane];
        float w = 1.f;
        if constexpr (!PRESCALED) w = rsqrtf((float)cursor[s * CSTRIDE] + 1.0f);
        const __half2* hp = (const __half2*)&v;
#pragma unroll
        for (int j = 0; j < 4; ++j) {
            float2 f = __half22float2(hp[j]);
            acc[2 * j]     = fmaf(f.x, w, acc[2 * j]);
            acc[2 * j + 1] = fmaf(f.y, w, acc[2 * j + 1]);
        }
    }

    float4 b0 = ((const float4*)bias)[2 * lane];
    float4 b1 = ((const float4*)bias)[2 * lane + 1];
    float r0 = fmaxf(fmaf(acc[0], dv, b0.x), 0.f);
    float r1 = fmaxf(fmaf(acc[1], dv, b0.y), 0.f);
    float r2 = fmaxf(fmaf(acc[2], dv, b0.z), 0.f);
    float r3 = fmaxf(fmaf(acc[3], dv, b0.w), 0.f);
    float r4 = fmaxf(fmaf(acc[4], dv, b1.x), 0.f);
    float r5 = fmaxf(fmaf(acc[5], dv, b1.y), 0.f);
    float r6 = fmaxf(fmaf(acc[6], dv, b1.z), 0.f);
    float r7 = fmaxf(fmaf(acc[7], dv, b1.w), 0.f);
    __half2 q0 = __floats2half2_rn(r0, r1);
    __half2 q1 = __floats2half2_rn(r2, r3);
    __half2 q2 = __floats2half2_rn(r4, r5);
    __half2 q3 = __floats2half2_rn(r6, r7);
    uint4 pk;
    pk.x = *(const unsigned int*)&q0;
    pk.y = *(const unsigned int*)&q1;
    pk.z = *(const unsigned int*)&q2;
    pk.w = *(const unsigned int*)&q3;
    ((uint4*)out)[(size_t)node * 16 + lane] = pk;
}

// ---------------- fused mean-pool + FC + sigmoid ----------------

__global__ __launch_bounds__(128) void pool_fc_k(const __half* __restrict__ h, const int* __restrict__ gstart,
                                                 const float* __restrict__ Wfc, const float* __restrict__ bfc,
                                                 float* __restrict__ out) {
    __shared__ float ps[CH];
    int g = blockIdx.x;
    int t = threadIdx.x;
    int beg = gstart[g], end = gstart[g + 1];
    int c = end - beg;
    float s = 0.f;
    for (int i = 0; i < c; ++i) s += __half2float(h[(size_t)(beg + i) * CH + t]);
    ps[t] = s / fmaxf((float)c, 1.0f);
    __syncthreads();
    if (t < OCH) {
        float acc = bfc[t];
#pragma unroll 8
        for (int k = 0; k < CH; ++k) acc = fmaf(ps[k], Wfc[k * OCH + t], acc);
        out[(size_t)g * OCH + t] = 1.0f / (1.0f + expf(-acc));
    }
}

extern "C" void kernel_launch(void* const* d_in, const int* in_sizes, int n_in,
                              void* d_out, int out_size, void* d_ws, size_t ws_size,
                              hipStream_t stream) {
    const float* x    = (const float*)d_in[0];
    const int*   edge = (const int*)d_in[1];
    const int*   batch= (const int*)d_in[2];
    const float* W1   = (const float*)d_in[3];
    const float* b1   = (const float*)d_in[4];
    const float* W2   = (const float*)d_in[5];
    const float* b2   = (const float*)d_in[6];
    const float* Wfc  = (const float*)d_in[7];
    const float* bfc  = (const float*)d_in[8];
    float* out = (float*)d_out;

    const int N = NN;
    const int E = in_sizes[1] / 2;
    const int* src = edge;
    const int* dst = edge + E;

    // workspace layout (16B alignment preserved in order)
    __half* h     = (__half*)d_ws;                     // N*CH halves
    __half* agg   = h + (size_t)N * CH;                // N*CH halves
    _Float16* Wt1 = (_Float16*)(agg + (size_t)N * CH); // CH*CH halves
    _Float16* Wt2 = Wt1 + CH * CH;                     // CH*CH halves
    int* cursor   = (int*)(Wt2 + CH * CH);             // N*CSTRIDE (3.2 MB, 64B/counter)
    int* gstart   = cursor + (size_t)N * CSTRIDE;      // NG+4 (padded to keep csr 16B-aligned)
    int* csr      = gstart + NG + 4;                   // N*CAP

    const int G = (N + 63) / 64;                 // gemm blocks (782)
    const int F = (E + 1023) / 1024;             // fill blocks (586), 4 edges/thread

    init_prep_k<<<(N * (CSTRIDE / 4) + 255) / 256, 256, 0, stream>>>(cursor, batch, N, gstart, W1, W2, Wt1, Wt2);
    gemm1_fill_k<<<F + G, 256, 0, stream>>>(x, Wt1, src, dst, cursor, csr, h, N, E, F);
    aggregate_k<false><<<(N + 15) / 16, 256, 0, stream>>>(h, cursor, csr, b1, agg, N);
    gemm2_k<<<G, 256, 0, stream>>>((const _Float16*)agg, Wt2, cursor, h, N);
    aggregate_k<true><<<(N + 15) / 16, 256, 0, stream>>>(h, cursor, csr, b2, agg, N);
    pool_fc_k<<<NG, 128, 0, stream>>>(agg, gstart, Wfc, bfc, out);
}

// Round 9
// 172.303 us; speedup vs baseline: 2.2608x; 1.0168x over previous
//
#include <hip/hip_runtime.h>
#include <hip/hip_fp16.h>
#include <math.h>

#define NN 50000
#define CH 128
#define NG 512
#define OCH 16
#define CAP 64        // bucket capacity per node; deg ~ Poisson(12), P(>=64) ~ 1e-30
#define NBINS 196     // bin = dst >> 8 (256 nodes per bin)
#define HB 147        // hist/scatter blocks, 4096 edges each

typedef _Float16 half8 __attribute__((ext_vector_type(8)));
typedef float f32x4 __attribute__((ext_vector_type(4)));

// ---------------- init: gstart binsearch + weight transpose/cvt (no memsets needed) ----------------

__global__ __launch_bounds__(256) void init_prep_k(const int* __restrict__ batch, int n,
                                                   int* __restrict__ gstart,
                                                   const float* __restrict__ W1, const float* __restrict__ W2,
                                                   _Float16* __restrict__ Wt1, _Float16* __restrict__ Wt2) {
    int i = blockIdx.x * blockDim.x + threadIdx.x;
    if (i <= NG) {
        int lo = 0, hi = n;
        while (lo < hi) {
            int mid = (lo + hi) >> 1;
            if (batch[mid] < i) lo = mid + 1; else hi = mid;
        }
        gstart[i] = lo;
    }
    if (i < CH * CH) {
        int k = i >> 7, c = i & 127;
        Wt1[c * CH + k] = (_Float16)W1[i];
        Wt2[c * CH + k] = (_Float16)W2[i];
    }
}

// ---------------- phase 1: per-block LDS histogram of dst bins ----------------

__global__ __launch_bounds__(256) void hist_k(const int* __restrict__ dst, int e, int* __restrict__ table) {
    __shared__ int hist[NBINS];
    for (int i = threadIdx.x; i < NBINS; i += 256) hist[i] = 0;
    __syncthreads();
#pragma unroll
    for (int j = 0; j < 4; ++j) {
        int idx = blockIdx.x * 4096 + j * 1024 + threadIdx.x * 4;
        if (idx + 3 < e) {
            int4 d = *(const int4*)&dst[idx];
            atomicAdd(&hist[d.x >> 8], 1);
            atomicAdd(&hist[d.y >> 8], 1);
            atomicAdd(&hist[d.z >> 8], 1);
            atomicAdd(&hist[d.w >> 8], 1);
        } else {
            for (int k = idx; k < e && k < idx + 4; ++k) atomicAdd(&hist[dst[k] >> 8], 1);
        }
    }
    __syncthreads();
    for (int i = threadIdx.x; i < NBINS; i += 256) table[blockIdx.x * NBINS + i] = hist[i];
}

// ---------------- phase 2: scan table -> per-(block,bin) offsets + bin_start ----------------

__global__ __launch_bounds__(256) void scanbins_k(int* __restrict__ table, int* __restrict__ bin_start) {
    __shared__ int tot[NBINS];
    __shared__ int sc[NBINS];
    int t = threadIdx.x;
    if (t < NBINS) {
        int run = 0;
        for (int b = 0; b < HB; ++b) {
            int v = table[b * NBINS + t];
            table[b * NBINS + t] = run;
            run += v;
        }
        tot[t] = run;
        sc[t] = run;
    }
    __syncthreads();
    for (int off = 1; off < NBINS; off <<= 1) {
        int u = (t >= off && t < NBINS) ? sc[t - off] : 0;
        __syncthreads();
        if (t < NBINS) sc[t] += u;
        __syncthreads();
    }
    if (t < NBINS) {
        int base = sc[t] - tot[t];
        bin_start[t] = base;
        if (t == NBINS - 1) bin_start[NBINS] = sc[t];
        for (int b = 0; b < HB; ++b) table[b * NBINS + t] += base;
    }
}

// ---------------- phase 3: scatter edges into bin-contiguous (dst,src) pairs (LDS cursors) ----------------

__global__ __launch_bounds__(256) void scatter_k(const int* __restrict__ src, const int* __restrict__ dst, int e,
                                                 const int* __restrict__ table, int2* __restrict__ binned) {
    __shared__ int cur[NBINS];
    for (int i = threadIdx.x; i < NBINS; i += 256) cur[i] = table[blockIdx.x * NBINS + i];
    __syncthreads();
#pragma unroll
    for (int j = 0; j < 4; ++j) {
        int idx = blockIdx.x * 4096 + j * 1024 + threadIdx.x * 4;
        if (idx + 3 < e) {
            int4 d = *(const int4*)&dst[idx];
            int4 s = *(const int4*)&src[idx];
            int p0 = atomicAdd(&cur[d.x >> 8], 1);
            int p1 = atomicAdd(&cur[d.y >> 8], 1);
            int p2 = atomicAdd(&cur[d.z >> 8], 1);
            int p3 = atomicAdd(&cur[d.w >> 8], 1);
            binned[p0] = make_int2(d.x, s.x);
            binned[p1] = make_int2(d.y, s.y);
            binned[p2] = make_int2(d.z, s.z);
            binned[p3] = make_int2(d.w, s.w);
        } else {
            for (int k = idx; k < e && k < idx + 4; ++k) {
                int d = dst[k];
                int p = atomicAdd(&cur[d >> 8], 1);
                binned[p] = make_int2(d, src[k]);
            }
        }
    }
}

// ---------------- MFMA GEMM body (as R7/R8, cursor dense) ----------------

template <typename AT, bool SCALE>
__device__ __forceinline__ void gemm_body(const AT* __restrict__ A, const _Float16* __restrict__ Wt,
                                          const int* __restrict__ cursor, __half* __restrict__ C,
                                          int n, int blk) {
    int wave = threadIdx.x >> 6;
    int lane = threadIdx.x & 63;
    int base = blk * 64 + wave * 16;
    if (base >= n) return;
    int ma = lane & 15;
    int kb = lane >> 4;

    f32x4 acc[8];
#pragma unroll
    for (int t = 0; t < 8; ++t) acc[t] = (f32x4){0.f, 0.f, 0.f, 0.f};

#pragma unroll
    for (int kk = 0; kk < 4; ++kk) {
        int k0 = kk * 32 + kb * 8;
        half8 af;
        if constexpr (sizeof(AT) == 4) {
            const float* ap = (const float*)A + (size_t)(base + ma) * CH + k0;
            float4 a0 = ((const float4*)ap)[0];
            float4 a1 = ((const float4*)ap)[1];
            af[0] = (_Float16)a0.x; af[1] = (_Float16)a0.y; af[2] = (_Float16)a0.z; af[3] = (_Float16)a0.w;
            af[4] = (_Float16)a1.x; af[5] = (_Float16)a1.y; af[6] = (_Float16)a1.z; af[7] = (_Float16)a1.w;
        } else {
            af = *(const half8*)((const _Float16*)A + (size_t)(base + ma) * CH + k0);
        }
#pragma unroll
        for (int tn = 0; tn < 8; ++tn) {
            half8 bf = *(const half8*)(Wt + (size_t)(tn * 16 + ma) * CH + k0);
            acc[tn] = __builtin_amdgcn_mfma_f32_16x16x32_f16(af, bf, acc[tn], 0, 0, 0);
        }
    }

    int r0 = base + kb * 4;
    float dv[4];
#pragma unroll
    for (int r = 0; r < 4; ++r) dv[r] = SCALE ? rsqrtf((float)cursor[r0 + r] + 1.0f) : 1.0f;
#pragma unroll
    for (int tn = 0; tn < 8; ++tn) {
#pragma unroll
        for (int r = 0; r < 4; ++r) {
            C[(size_t)(r0 + r) * CH + tn * 16 + ma] = __float2half(acc[tn][r] * dv[r]);
        }
    }
}

// ---------------- phase 4 fused: bucket build (blocks 0..NBINS) + gemm1 (rest) ----------------

__global__ __launch_bounds__(256) void bucket_gemm1_k(const int2* __restrict__ binned, const int* __restrict__ bin_start,
                                                      int* __restrict__ cursor, int* __restrict__ csr,
                                                      const float* __restrict__ x, const _Float16* __restrict__ Wt1,
                                                      __half* __restrict__ h, int n) {
    if ((int)blockIdx.x < NBINS) {
        __shared__ int cur2[256];
        cur2[threadIdx.x] = 0;
        __syncthreads();
        int lo = bin_start[blockIdx.x], hi = bin_start[blockIdx.x + 1];
        for (int i = lo + threadIdx.x; i < hi; i += 256) {
            int2 p = binned[i];
            int pos = atomicAdd(&cur2[p.x & 255], 1);
            if (pos < CAP) csr[(size_t)p.x * CAP + pos] = p.y;
        }
        __syncthreads();
        int node = blockIdx.x * 256 + threadIdx.x;
        if (node < n) cursor[node] = cur2[threadIdx.x];
    } else {
        gemm_body<float, false>(x, Wt1, nullptr, h, n, blockIdx.x - NBINS);
    }
}

// ---------------- standalone gemm for layer 2 (A fp16, scaled epilogue) ----------------

__global__ __launch_bounds__(256) void gemm2_k(const _Float16* __restrict__ A, const _Float16* __restrict__ Wt,
                                               const int* __restrict__ cursor, __half* __restrict__ C, int n) {
    gemm_body<_Float16, true>(A, Wt, cursor, C, n, blockIdx.x);
}

// ---------------- aggregation (fp16 gather, bucket rows, int4 index preload) ----------------

template <bool PRESCALED>
__global__ __launch_bounds__(256) void aggregate_k(const __half* __restrict__ ht,
                                                   const int* __restrict__ cursor, const int* __restrict__ csr,
                                                   const float* __restrict__ bias, __half* __restrict__ out, int n) {
    int node = blockIdx.x * 16 + (threadIdx.x >> 4);
    if (node >= n) return;
    int lane = threadIdx.x & 15;
    const uint4* H = (const uint4*)ht;
    int deg = cursor[node];
    float dv = rsqrtf((float)deg + 1.0f);
    int degc = deg > CAP ? CAP : deg;

    float acc[8];
    {
        uint4 v = H[(size_t)node * 16 + lane];
        const __half2* hp = (const __half2*)&v;
        float selfs = PRESCALED ? 1.0f : dv;
#pragma unroll
        for (int j = 0; j < 4; ++j) {
            float2 f = __half22float2(hp[j]);
            acc[2 * j] = f.x * selfs; acc[2 * j + 1] = f.y * selfs;
        }
    }

    const int4* row4 = (const int4*)(csr + (size_t)node * CAP);
    int i = 0;
    for (; i + 4 <= degc; i += 4) {
        int4 s4 = row4[i >> 2];
        uint4 v0 = H[(size_t)s4.x * 16 + lane];
        uint4 v1 = H[(size_t)s4.y * 16 + lane];
        uint4 v2 = H[(size_t)s4.z * 16 + lane];
        uint4 v3 = H[(size_t)s4.w * 16 + lane];
        float w0 = 1.f, w1 = 1.f, w2 = 1.f, w3 = 1.f;
        if constexpr (!PRESCALED) {
            w0 = rsqrtf((float)cursor[s4.x] + 1.0f);
            w1 = rsqrtf((float)cursor[s4.y] + 1.0f);
            w2 = rsqrtf((float)cursor[s4.z] + 1.0f);
            w3 = rsqrtf((float)cursor[s4.w] + 1.0f);
        }
        const __half2* p0 = (const __half2*)&v0;
        const __half2* p1 = (const __half2*)&v1;
        const __half2* p2 = (const __half2*)&v2;
        const __half2* p3 = (const __half2*)&v3;
#pragma unroll
        for (int j = 0; j < 4; ++j) {
            float2 f0 = __half22float2(p0[j]);
            float2 f1 = __half22float2(p1[j]);
            float2 f2 = __half22float2(p2[j]);
            float2 f3 = __half22float2(p3[j]);
            acc[2 * j]     = fmaf(f0.x, w0, acc[2 * j]);
            acc[2 * j + 1] = fmaf(f0.y, w0, acc[2 * j + 1]);
            acc[2 * j]     = fmaf(f1.x, w1, acc[2 * j]);
            acc[2 * j + 1] = fmaf(f1.y, w1, acc[2 * j + 1]);
            acc[2 * j]     = fmaf(f2.x, w2, acc[2 * j]);
            acc[2 * j + 1] = fmaf(f2.y, w2, acc[2 * j + 1]);
            acc[2 * j]     = fmaf(f3.x, w3, acc[2 * j]);
            acc[2 * j + 1] = fmaf(f3.y, w3, acc[2 * j + 1]);
        }
    }
    for (; i < degc; ++i) {
        int s = csr[(size_t)node * CAP + i];
        uint4 v = H[(size_t)s * 16 + lane];
        float w = 1.f;
        if constexpr (!PRESCALED) w = rsqrtf((float)cursor[s] + 1.0f);
        const __half2* hp = (const __half2*)&v;
#pragma unroll
        for (int j = 0; j < 4; ++j) {
            float2 f = __half22float2(hp[j]);
            acc[2 * j]     = fmaf(f.x, w, acc[2 * j]);
            acc[2 * j + 1] = fmaf(f.y, w, acc[2 * j + 1]);
        }
    }

    float4 b0 = ((const float4*)bias)[2 * lane];
    float4 b1 = ((const float4*)bias)[2 * lane + 1];
    float r0 = fmaxf(fmaf(acc[0], dv, b0.x), 0.f);
    float r1 = fmaxf(fmaf(acc[1], dv, b0.y), 0.f);
    float r2 = fmaxf(fmaf(acc[2], dv, b0.z), 0.f);
    float r3 = fmaxf(fmaf(acc[3], dv, b0.w), 0.f);
    float r4 = fmaxf(fmaf(acc[4], dv, b1.x), 0.f);
    float r5 = fmaxf(fmaf(acc[5], dv, b1.y), 0.f);
    float r6 = fmaxf(fmaf(acc[6], dv, b1.z), 0.f);
    float r7 = fmaxf(fmaf(acc[7], dv, b1.w), 0.f);
    __half2 q0 = __floats2half2_rn(r0, r1);
    __half2 q1 = __floats2half2_rn(r2, r3);
    __half2 q2 = __floats2half2_rn(r4, r5);
    __half2 q3 = __floats2half2_rn(r6, r7);
    uint4 pk;
    pk.x = *(const unsigned int*)&q0;
    pk.y = *(const unsigned int*)&q1;
    pk.z = *(const unsigned int*)&q2;
    pk.w = *(const unsigned int*)&q3;
    ((uint4*)out)[(size_t)node * 16 + lane] = pk;
}

// ---------------- fused mean-pool + FC + sigmoid ----------------

__global__ __launch_bounds__(128) void pool_fc_k(const __half* __restrict__ h, const int* __restrict__ gstart,
                                                 const float* __restrict__ Wfc, const float* __restrict__ bfc,
                                                 float* __restrict__ out) {
    __shared__ float ps[CH];
    int g = blockIdx.x;
    int t = threadIdx.x;
    int beg = gstart[g], end = gstart[g + 1];
    int c = end - beg;
    float s = 0.f;
    for (int i = 0; i < c; ++i) s += __half2float(h[(size_t)(beg + i) * CH + t]);
    ps[t] = s / fmaxf((float)c, 1.0f);
    __syncthreads();
    if (t < OCH) {
        float acc = bfc[t];
#pragma unroll 8
        for (int k = 0; k < CH; ++k) acc = fmaf(ps[k], Wfc[k * OCH + t], acc);
        out[(size_t)g * OCH + t] = 1.0f / (1.0f + expf(-acc));
    }
}

extern "C" void kernel_launch(void* const* d_in, const int* in_sizes, int n_in,
                              void* d_out, int out_size, void* d_ws, size_t ws_size,
                              hipStream_t stream) {
    const float* x    = (const float*)d_in[0];
    const int*   edge = (const int*)d_in[1];
    const int*   batch= (const int*)d_in[2];
    const float* W1   = (const float*)d_in[3];
    const float* b1   = (const float*)d_in[4];
    const float* W2   = (const float*)d_in[5];
    const float* b2   = (const float*)d_in[6];
    const float* Wfc  = (const float*)d_in[7];
    const float* bfc  = (const float*)d_in[8];
    float* out = (float*)d_out;

    const int N = NN;
    const int E = in_sizes[1] / 2;
    const int* src = edge;
    const int* dst = edge + E;

    // workspace layout (16B alignment preserved in order)
    __half* h      = (__half*)d_ws;                      // N*CH halves
    __half* agg    = h + (size_t)N * CH;                 // N*CH halves
    _Float16* Wt1  = (_Float16*)(agg + (size_t)N * CH);  // CH*CH
    _Float16* Wt2  = Wt1 + CH * CH;                      // CH*CH
    int* cursor    = (int*)(Wt2 + CH * CH);              // N
    int* gstart    = cursor + N;                         // NG+4
    int* csr       = gstart + NG + 4;                    // N*CAP
    int* table     = csr + (size_t)N * CAP;              // HB*NBINS (28812)
    int* bin_start = table + HB * NBINS;                 // NBINS+4 -> pad 200
    int2* binned   = (int2*)(bin_start + 200);           // E pairs

    const int G = (N + 63) / 64;   // 782 gemm blocks

    init_prep_k<<<(CH * CH + 255) / 256, 256, 0, stream>>>(batch, N, gstart, W1, W2, Wt1, Wt2);
    hist_k<<<HB, 256, 0, stream>>>(dst, E, table);
    scanbins_k<<<1, 256, 0, stream>>>(table, bin_start);
    scatter_k<<<HB, 256, 0, stream>>>(src, dst, E, table, binned);
    bucket_gemm1_k<<<NBINS + G, 256, 0, stream>>>(binned, bin_start, cursor, csr, x, Wt1, h, N);
    aggregate_k<false><<<(N + 15) / 16, 256, 0, stream>>>(h, cursor, csr, b1, agg, N);
    gemm2_k<<<G, 256, 0, stream>>>((const _Float16*)agg, Wt2, cursor, h, N);
    aggregate_k<true><<<(N + 15) / 16, 256, 0, stream>>>(h, cursor, csr, b2, agg, N);
    pool_fc_k<<<NG, 128, 0, stream>>>(agg, gstart, Wfc, bfc, out);
}

// Round 10
// 154.389 us; speedup vs baseline: 2.5231x; 1.1160x over previous
//
#include <hip/hip_runtime.h>
#include <hip/hip_fp16.h>
#include <math.h>

#define NN 50000
#define CH 128
#define NG 512
#define OCH 16
#define CAP 64        // bucket capacity per node; deg ~ Poisson(12), P(>=64) ~ 1e-30
#define NBINS 196     // bin = dst >> 8 (256 nodes per bin)
#define HB 147        // hist/scatter blocks, 4096 edges each

typedef _Float16 half8 __attribute__((ext_vector_type(8)));
typedef float f32x4 __attribute__((ext_vector_type(4)));

// ---------------- phase 1 (fused): per-block LDS histogram  +  init roles ----------------
// blocks [0,HB): histogram of dst bins -> tableT[bin][block]
// blocks [HB, HB+66): gstart binsearch + weight transpose/cvt

__global__ __launch_bounds__(256) void hist_init_k(const int* __restrict__ dst, int e, int* __restrict__ tableT,
                                                   const int* __restrict__ batch, int n, int* __restrict__ gstart,
                                                   const float* __restrict__ W1, const float* __restrict__ W2,
                                                   _Float16* __restrict__ Wt1, _Float16* __restrict__ Wt2) {
    if ((int)blockIdx.x < HB) {
        __shared__ int hist[NBINS];
        for (int i = threadIdx.x; i < NBINS; i += 256) hist[i] = 0;
        __syncthreads();
#pragma unroll
        for (int j = 0; j < 4; ++j) {
            int idx = blockIdx.x * 4096 + j * 1024 + threadIdx.x * 4;
            if (idx + 3 < e) {
                int4 d = *(const int4*)&dst[idx];
                atomicAdd(&hist[d.x >> 8], 1);
                atomicAdd(&hist[d.y >> 8], 1);
                atomicAdd(&hist[d.z >> 8], 1);
                atomicAdd(&hist[d.w >> 8], 1);
            } else {
                for (int k = idx; k < e && k < idx + 4; ++k) atomicAdd(&hist[dst[k] >> 8], 1);
            }
        }
        __syncthreads();
        for (int i = threadIdx.x; i < NBINS; i += 256) tableT[i * HB + blockIdx.x] = hist[i];
    } else {
        int i = ((int)blockIdx.x - HB) * 256 + threadIdx.x;
        if (i <= NG) {
            int lo = 0, hi = n;
            while (lo < hi) {
                int mid = (lo + hi) >> 1;
                if (batch[mid] < i) lo = mid + 1; else hi = mid;
            }
            gstart[i] = lo;
        }
        if (i < CH * CH) {
            int k = i >> 7, c = i & 127;
            Wt1[c * CH + k] = (_Float16)W1[i];
            Wt2[c * CH + k] = (_Float16)W2[i];
        }
    }
}

// ---------------- phase 2a: per-bin wave scan over HB block counts (196 waves) ----------------

__global__ __launch_bounds__(256) void scanA_k(int* __restrict__ tableT, int* __restrict__ binsum) {
    int w = threadIdx.x >> 6, lane = threadIdx.x & 63;
    int bin = blockIdx.x * 4 + w;            // 49 blocks * 4 waves = 196 = NBINS
    int* row = tableT + bin * HB;
    int b3 = lane * 3;
    int v0 = (b3     < HB) ? row[b3]     : 0;
    int v1 = (b3 + 1 < HB) ? row[b3 + 1] : 0;
    int v2 = (b3 + 2 < HB) ? row[b3 + 2] : 0;
    int s = v0 + v1 + v2;
    int x = s;
#pragma unroll
    for (int off = 1; off < 64; off <<= 1) {
        int y = __shfl_up(x, off);
        if (lane >= off) x += y;
    }
    int excl = x - s;
    if (b3     < HB) row[b3]     = excl;
    if (b3 + 1 < HB) row[b3 + 1] = excl + v0;
    if (b3 + 2 < HB) row[b3 + 2] = excl + v0 + v1;
    if (lane == 63) binsum[bin] = x;
}

// ---------------- phase 2b: scan 196 bin totals -> bin_start ----------------

__global__ __launch_bounds__(256) void scanB_k(const int* __restrict__ binsum, int* __restrict__ bin_start) {
    __shared__ int s[256];
    int t = threadIdx.x;
    int v = (t < NBINS) ? binsum[t] : 0;
    s[t] = v;
    __syncthreads();
    for (int off = 1; off < 256; off <<= 1) {
        int u = (t >= off) ? s[t - off] : 0;
        __syncthreads();
        s[t] += u;
        __syncthreads();
    }
    if (t < NBINS) bin_start[t] = s[t] - v;
    if (t == NBINS - 1) bin_start[NBINS] = s[t];
}

// ---------------- phase 3: scatter edges into bin-contiguous packed words (LDS cursors) ----------------
// pack: src (16 bits) | (dst & 255) << 16   (src < 50000 < 65536)

__global__ __launch_bounds__(256) void scatter_k(const int* __restrict__ src, const int* __restrict__ dst, int e,
                                                 const int* __restrict__ tableT, const int* __restrict__ bin_start,
                                                 unsigned int* __restrict__ binned) {
    __shared__ int cur[NBINS];
    for (int i = threadIdx.x; i < NBINS; i += 256) cur[i] = bin_start[i] + tableT[i * HB + blockIdx.x];
    __syncthreads();
#pragma unroll
    for (int j = 0; j < 4; ++j) {
        int idx = blockIdx.x * 4096 + j * 1024 + threadIdx.x * 4;
        if (idx + 3 < e) {
            int4 d = *(const int4*)&dst[idx];
            int4 s = *(const int4*)&src[idx];
            int p0 = atomicAdd(&cur[d.x >> 8], 1);
            int p1 = atomicAdd(&cur[d.y >> 8], 1);
            int p2 = atomicAdd(&cur[d.z >> 8], 1);
            int p3 = atomicAdd(&cur[d.w >> 8], 1);
            binned[p0] = (unsigned)s.x | ((unsigned)(d.x & 255) << 16);
            binned[p1] = (unsigned)s.y | ((unsigned)(d.y & 255) << 16);
            binned[p2] = (unsigned)s.z | ((unsigned)(d.z & 255) << 16);
            binned[p3] = (unsigned)s.w | ((unsigned)(d.w & 255) << 16);
        } else {
            for (int k = idx; k < e && k < idx + 4; ++k) {
                int d = dst[k];
                int p = atomicAdd(&cur[d >> 8], 1);
                binned[p] = (unsigned)src[k] | ((unsigned)(d & 255) << 16);
            }
        }
    }
}

// ---------------- MFMA GEMM body ----------------

template <typename AT, bool SCALE>
__device__ __forceinline__ void gemm_body(const AT* __restrict__ A, const _Float16* __restrict__ Wt,
                                          const int* __restrict__ cursor, __half* __restrict__ C,
                                          int n, int blk) {
    int wave = threadIdx.x >> 6;
    int lane = threadIdx.x & 63;
    int base = blk * 64 + wave * 16;
    if (base >= n) return;
    int ma = lane & 15;
    int kb = lane >> 4;

    f32x4 acc[8];
#pragma unroll
    for (int t = 0; t < 8; ++t) acc[t] = (f32x4){0.f, 0.f, 0.f, 0.f};

#pragma unroll
    for (int kk = 0; kk < 4; ++kk) {
        int k0 = kk * 32 + kb * 8;
        half8 af;
        if constexpr (sizeof(AT) == 4) {
            const float* ap = (const float*)A + (size_t)(base + ma) * CH + k0;
            float4 a0 = ((const float4*)ap)[0];
            float4 a1 = ((const float4*)ap)[1];
            af[0] = (_Float16)a0.x; af[1] = (_Float16)a0.y; af[2] = (_Float16)a0.z; af[3] = (_Float16)a0.w;
            af[4] = (_Float16)a1.x; af[5] = (_Float16)a1.y; af[6] = (_Float16)a1.z; af[7] = (_Float16)a1.w;
        } else {
            af = *(const half8*)((const _Float16*)A + (size_t)(base + ma) * CH + k0);
        }
#pragma unroll
        for (int tn = 0; tn < 8; ++tn) {
            half8 bf = *(const half8*)(Wt + (size_t)(tn * 16 + ma) * CH + k0);
            acc[tn] = __builtin_amdgcn_mfma_f32_16x16x32_f16(af, bf, acc[tn], 0, 0, 0);
        }
    }

    int r0 = base + kb * 4;
    float dv[4];
#pragma unroll
    for (int r = 0; r < 4; ++r) dv[r] = SCALE ? rsqrtf((float)cursor[r0 + r] + 1.0f) : 1.0f;
#pragma unroll
    for (int tn = 0; tn < 8; ++tn) {
#pragma unroll
        for (int r = 0; r < 4; ++r) {
            C[(size_t)(r0 + r) * CH + tn * 16 + ma] = __float2half(acc[tn][r] * dv[r]);
        }
    }
}

// ---------------- phase 4 fused: bucket build (blocks 0..NBINS) + gemm1 (rest) ----------------

__global__ __launch_bounds__(256) void bucket_gemm1_k(const unsigned int* __restrict__ binned,
                                                      const int* __restrict__ bin_start,
                                                      int* __restrict__ cursor, int* __restrict__ csr,
                                                      const float* __restrict__ x, const _Float16* __restrict__ Wt1,
                                                      __half* __restrict__ h, int n) {
    if ((int)blockIdx.x < NBINS) {
        __shared__ int cur2[256];
        cur2[threadIdx.x] = 0;
        __syncthreads();
        int lo = bin_start[blockIdx.x], hi = bin_start[blockIdx.x + 1];
        for (int i = lo + threadIdx.x; i < hi; i += 256) {
            unsigned int p = binned[i];
            int local = p >> 16;                       // dst & 255
            int node = (blockIdx.x << 8) | local;
            int pos = atomicAdd(&cur2[local], 1);
            if (pos < CAP) csr[(size_t)node * CAP + pos] = (int)(p & 0xFFFFu);
        }
        __syncthreads();
        int node = blockIdx.x * 256 + threadIdx.x;
        if (node < n) cursor[node] = cur2[threadIdx.x];
    } else {
        gemm_body<float, false>(x, Wt1, nullptr, h, n, blockIdx.x - NBINS);
    }
}

// ---------------- standalone gemm for layer 2 (A fp16, scaled epilogue) ----------------

__global__ __launch_bounds__(256) void gemm2_k(const _Float16* __restrict__ A, const _Float16* __restrict__ Wt,
                                               const int* __restrict__ cursor, __half* __restrict__ C, int n) {
    gemm_body<_Float16, true>(A, Wt, cursor, C, n, blockIdx.x);
}

// ---------------- aggregation (fp16 gather, bucket rows, int4 index preload) ----------------

template <bool PRESCALED>
__global__ __launch_bounds__(256) void aggregate_k(const __half* __restrict__ ht,
                                                   const int* __restrict__ cursor, const int* __restrict__ csr,
                                                   const float* __restrict__ bias, __half* __restrict__ out, int n) {
    int node = blockIdx.x * 16 + (threadIdx.x >> 4);
    if (node >= n) return;
    int lane = threadIdx.x & 15;
    const uint4* H = (const uint4*)ht;
    int deg = cursor[node];
    float dv = rsqrtf((float)deg + 1.0f);
    int degc = deg > CAP ? CAP : deg;

    float acc[8];
    {
        uint4 v = H[(size_t)node * 16 + lane];
        const __half2* hp = (const __half2*)&v;
        float selfs = PRESCALED ? 1.0f : dv;
#pragma unroll
        for (int j = 0; j < 4; ++j) {
            float2 f = __half22float2(hp[j]);
            acc[2 * j] = f.x * selfs; acc[2 * j + 1] = f.y * selfs;
        }
    }

    const int4* row4 = (const int4*)(csr + (size_t)node * CAP);
    int i = 0;
    for (; i + 4 <= degc; i += 4) {
        int4 s4 = row4[i >> 2];
        uint4 v0 = H[(size_t)s4.x * 16 + lane];
        uint4 v1 = H[(size_t)s4.y * 16 + lane];
        uint4 v2 = H[(size_t)s4.z * 16 + lane];
        uint4 v3 = H[(size_t)s4.w * 16 + lane];
        float w0 = 1.f, w1 = 1.f, w2 = 1.f, w3 = 1.f;
        if constexpr (!PRESCALED) {
            w0 = rsqrtf((float)cursor[s4.x] + 1.0f);
            w1 = rsqrtf((float)cursor[s4.y] + 1.0f);
            w2 = rsqrtf((float)cursor[s4.z] + 1.0f);
            w3 = rsqrtf((float)cursor[s4.w] + 1.0f);
        }
        const __half2* p0 = (const __half2*)&v0;
        const __half2* p1 = (const __half2*)&v1;
        const __half2* p2 = (const __half2*)&v2;
        const __half2* p3 = (const __half2*)&v3;
#pragma unroll
        for (int j = 0; j < 4; ++j) {
            float2 f0 = __half22float2(p0[j]);
            float2 f1 = __half22float2(p1[j]);
            float2 f2 = __half22float2(p2[j]);
            float2 f3 = __half22float2(p3[j]);
            acc[2 * j]     = fmaf(f0.x, w0, acc[2 * j]);
            acc[2 * j + 1] = fmaf(f0.y, w0, acc[2 * j + 1]);
            acc[2 * j]     = fmaf(f1.x, w1, acc[2 * j]);
            acc[2 * j + 1] = fmaf(f1.y, w1, acc[2 * j + 1]);
            acc[2 * j]     = fmaf(f2.x, w2, acc[2 * j]);
            acc[2 * j + 1] = fmaf(f2.y, w2, acc[2 * j + 1]);
            acc[2 * j]     = fmaf(f3.x, w3, acc[2 * j]);
            acc[2 * j + 1] = fmaf(f3.y, w3, acc[2 * j + 1]);
        }
    }
    for (; i < degc; ++i) {
        int s = csr[(size_t)node * CAP + i];
        uint4 v = H[(size_t)s * 16 + lane];
        float w = 1.f;
        if constexpr (!PRESCALED) w = rsqrtf((float)cursor[s] + 1.0f);
        const __half2* hp = (const __half2*)&v;
#pragma unroll
        for (int j = 0; j < 4; ++j) {
            float2 f = __half22float2(hp[j]);
            acc[2 * j]     = fmaf(f.x, w, acc[2 * j]);
            acc[2 * j + 1] = fmaf(f.y, w, acc[2 * j + 1]);
        }
    }

    float4 b0 = ((const float4*)bias)[2 * lane];
    float4 b1 = ((const float4*)bias)[2 * lane + 1];
    float r0 = fmaxf(fmaf(acc[0], dv, b0.x), 0.f);
    float r1 = fmaxf(fmaf(acc[1], dv, b0.y), 0.f);
    float r2 = fmaxf(fmaf(acc[2], dv, b0.z), 0.f);
    float r3 = fmaxf(fmaf(acc[3], dv, b0.w), 0.f);
    float r4 = fmaxf(fmaf(acc[4], dv, b1.x), 0.f);
    float r5 = fmaxf(fmaf(acc[5], dv, b1.y), 0.f);
    float r6 = fmaxf(fmaf(acc[6], dv, b1.z), 0.f);
    float r7 = fmaxf(fmaf(acc[7], dv, b1.w), 0.f);
    __half2 q0 = __floats2half2_rn(r0, r1);
    __half2 q1 = __floats2half2_rn(r2, r3);
    __half2 q2 = __floats2half2_rn(r4, r5);
    __half2 q3 = __floats2half2_rn(r6, r7);
    uint4 pk;
    pk.x = *(const unsigned int*)&q0;
    pk.y = *(const unsigned int*)&q1;
    pk.z = *(const unsigned int*)&q2;
    pk.w = *(const unsigned int*)&q3;
    ((uint4*)out)[(size_t)node * 16 + lane] = pk;
}

// ---------------- fused mean-pool + FC + sigmoid ----------------

__global__ __launch_bounds__(128) void pool_fc_k(const __half* __restrict__ h, const int* __restrict__ gstart,
                                                 const float* __restrict__ Wfc, const float* __restrict__ bfc,
                                                 float* __restrict__ out) {
    __shared__ float ps[CH];
    int g = blockIdx.x;
    int t = threadIdx.x;
    int beg = gstart[g], end = gstart[g + 1];
    int c = end - beg;
    float s = 0.f;
    for (int i = 0; i < c; ++i) s += __half2float(h[(size_t)(beg + i) * CH + t]);
    ps[t] = s / fmaxf((float)c, 1.0f);
    __syncthreads();
    if (t < OCH) {
        float acc = bfc[t];
#pragma unroll 8
        for (int k = 0; k < CH; ++k) acc = fmaf(ps[k], Wfc[k * OCH + t], acc);
        out[(size_t)g * OCH + t] = 1.0f / (1.0f + expf(-acc));
    }
}

extern "C" void kernel_launch(void* const* d_in, const int* in_sizes, int n_in,
                              void* d_out, int out_size, void* d_ws, size_t ws_size,
                              hipStream_t stream) {
    const float* x    = (const float*)d_in[0];
    const int*   edge = (const int*)d_in[1];
    const int*   batch= (const int*)d_in[2];
    const float* W1   = (const float*)d_in[3];
    const float* b1   = (const float*)d_in[4];
    const float* W2   = (const float*)d_in[5];
    const float* b2   = (const float*)d_in[6];
    const float* Wfc  = (const float*)d_in[7];
    const float* bfc  = (const float*)d_in[8];
    float* out = (float*)d_out;

    const int N = NN;
    const int E = in_sizes[1] / 2;
    const int* src = edge;
    const int* dst = edge + E;

    // workspace layout (16B alignment preserved in order)
    __half* h      = (__half*)d_ws;                      // N*CH halves
    __half* agg    = h + (size_t)N * CH;                 // N*CH halves
    _Float16* Wt1  = (_Float16*)(agg + (size_t)N * CH);  // CH*CH
    _Float16* Wt2  = Wt1 + CH * CH;                      // CH*CH
    int* cursor    = (int*)(Wt2 + CH * CH);              // N
    int* gstart    = cursor + N;                         // NG+4
    int* csr       = gstart + NG + 4;                    // N*CAP
    int* tableT    = csr + (size_t)N * CAP;              // NBINS*HB (28812)
    int* binsum    = tableT + NBINS * HB;                // 196 -> pad 256
    int* bin_start = binsum + 256;                       // 197 -> pad 208
    unsigned int* binned = (unsigned int*)(bin_start + 208);  // E packed words

    const int G = (N + 63) / 64;   // 782 gemm blocks

    hist_init_k<<<HB + 66, 256, 0, stream>>>(dst, E, tableT, batch, N, gstart, W1, W2, Wt1, Wt2);
    scanA_k<<<49, 256, 0, stream>>>(tableT, binsum);
    scanB_k<<<1, 256, 0, stream>>>(binsum, bin_start);
    scatter_k<<<HB, 256, 0, stream>>>(src, dst, E, tableT, bin_start, binned);
    bucket_gemm1_k<<<NBINS + G, 256, 0, stream>>>(binned, bin_start, cursor, csr, x, Wt1, h, N);
    aggregate_k<false><<<(N + 15) / 16, 256, 0, stream>>>(h, cursor, csr, b1, agg, N);
    gemm2_k<<<G, 256, 0, stream>>>((const _Float16*)agg, Wt2, cursor, h, N);
    aggregate_k<true><<<(N + 15) / 16, 256, 0, stream>>>(h, cursor, csr, b2, agg, N);
    pool_fc_k<<<NG, 128, 0, stream>>>(agg, gstart, Wfc, bfc, out);
}

// Round 11
// 126.625 us; speedup vs baseline: 3.0763x; 1.2193x over previous
//
#include <hip/hip_runtime.h>
#include <hip/hip_fp16.h>
#include <math.h>

#define NN 50000
#define CH 128
#define NG 512
#define OCH 16
#define CAP 64        // bucket capacity per node; deg ~ Poisson(12), P(>=64) ~ 1e-30
#define NBINS 196     // bin = dst >> 8 (256 nodes per bin)
#define HB 147        // hist/scatter blocks, 4096 edges each

typedef _Float16 half8 __attribute__((ext_vector_type(8)));
typedef float f32x4 __attribute__((ext_vector_type(4)));
typedef float f32x2 __attribute__((ext_vector_type(2)));

// ---- fp8 e4m3 helpers (HW cvt, gfx940+ insts; OCP on gfx950) ----

__device__ __forceinline__ void unpack_fp8x8(uint2 v, float* o) {
    f32x2 a = __builtin_amdgcn_cvt_pk_f32_fp8((int)v.x, false);
    f32x2 b = __builtin_amdgcn_cvt_pk_f32_fp8((int)v.x, true);
    f32x2 c = __builtin_amdgcn_cvt_pk_f32_fp8((int)v.y, false);
    f32x2 d = __builtin_amdgcn_cvt_pk_f32_fp8((int)v.y, true);
    o[0] = a[0]; o[1] = a[1]; o[2] = b[0]; o[3] = b[1];
    o[4] = c[0]; o[5] = c[1]; o[6] = d[0]; o[7] = d[1];
}

__device__ __forceinline__ unsigned char f32_to_fp8(float v) {
    int r = __builtin_amdgcn_cvt_pk_fp8_f32(v, v, 0, false);
    return (unsigned char)(r & 0xFF);
}

// ---------------- phase 1 (fused): per-block LDS histogram + init roles ----------------

__global__ __launch_bounds__(256) void hist_init_k(const int* __restrict__ dst, int e, int* __restrict__ tableT,
                                                   const int* __restrict__ batch, int n, int* __restrict__ gstart,
                                                   const float* __restrict__ W1, const float* __restrict__ W2,
                                                   _Float16* __restrict__ Wt1, _Float16* __restrict__ Wt2) {
    if ((int)blockIdx.x < HB) {
        __shared__ int hist[NBINS];
        for (int i = threadIdx.x; i < NBINS; i += 256) hist[i] = 0;
        __syncthreads();
#pragma unroll
        for (int j = 0; j < 4; ++j) {
            int idx = blockIdx.x * 4096 + j * 1024 + threadIdx.x * 4;
            if (idx + 3 < e) {
                int4 d = *(const int4*)&dst[idx];
                atomicAdd(&hist[d.x >> 8], 1);
                atomicAdd(&hist[d.y >> 8], 1);
                atomicAdd(&hist[d.z >> 8], 1);
                atomicAdd(&hist[d.w >> 8], 1);
            } else {
                for (int k = idx; k < e && k < idx + 4; ++k) atomicAdd(&hist[dst[k] >> 8], 1);
            }
        }
        __syncthreads();
        for (int i = threadIdx.x; i < NBINS; i += 256) tableT[i * HB + blockIdx.x] = hist[i];
    } else {
        int i = ((int)blockIdx.x - HB) * 256 + threadIdx.x;
        if (i <= NG) {
            int lo = 0, hi = n;
            while (lo < hi) {
                int mid = (lo + hi) >> 1;
                if (batch[mid] < i) lo = mid + 1; else hi = mid;
            }
            gstart[i] = lo;
        }
        if (i < CH * CH) {
            int k = i >> 7, c = i & 127;
            Wt1[c * CH + k] = (_Float16)W1[i];
            Wt2[c * CH + k] = (_Float16)W2[i];
        }
    }
}

// ---------------- phase 2a: per-bin wave scan over HB block counts (196 waves) ----------------

__global__ __launch_bounds__(256) void scanA_k(int* __restrict__ tableT, int* __restrict__ binsum) {
    int w = threadIdx.x >> 6, lane = threadIdx.x & 63;
    int bin = blockIdx.x * 4 + w;
    int* row = tableT + bin * HB;
    int b3 = lane * 3;
    int v0 = (b3     < HB) ? row[b3]     : 0;
    int v1 = (b3 + 1 < HB) ? row[b3 + 1] : 0;
    int v2 = (b3 + 2 < HB) ? row[b3 + 2] : 0;
    int s = v0 + v1 + v2;
    int x = s;
#pragma unroll
    for (int off = 1; off < 64; off <<= 1) {
        int y = __shfl_up(x, off);
        if (lane >= off) x += y;
    }
    int excl = x - s;
    if (b3     < HB) row[b3]     = excl;
    if (b3 + 1 < HB) row[b3 + 1] = excl + v0;
    if (b3 + 2 < HB) row[b3 + 2] = excl + v0 + v1;
    if (lane == 63) binsum[bin] = x;
}

// ---------------- phase 2b: scan 196 bin totals -> bin_start ----------------

__global__ __launch_bounds__(256) void scanB_k(const int* __restrict__ binsum, int* __restrict__ bin_start) {
    __shared__ int s[256];
    int t = threadIdx.x;
    int v = (t < NBINS) ? binsum[t] : 0;
    s[t] = v;
    __syncthreads();
    for (int off = 1; off < 256; off <<= 1) {
        int u = (t >= off) ? s[t - off] : 0;
        __syncthreads();
        s[t] += u;
        __syncthreads();
    }
    if (t < NBINS) bin_start[t] = s[t] - v;
    if (t == NBINS - 1) bin_start[NBINS] = s[t];
}

// ---------------- phase 3: scatter edges into bin-contiguous packed words ----------------

__global__ __launch_bounds__(256) void scatter_k(const int* __restrict__ src, const int* __restrict__ dst, int e,
                                                 const int* __restrict__ tableT, const int* __restrict__ bin_start,
                                                 unsigned int* __restrict__ binned) {
    __shared__ int cur[NBINS];
    for (int i = threadIdx.x; i < NBINS; i += 256) cur[i] = bin_start[i] + tableT[i * HB + blockIdx.x];
    __syncthreads();
#pragma unroll
    for (int j = 0; j < 4; ++j) {
        int idx = blockIdx.x * 4096 + j * 1024 + threadIdx.x * 4;
        if (idx + 3 < e) {
            int4 d = *(const int4*)&dst[idx];
            int4 s = *(const int4*)&src[idx];
            int p0 = atomicAdd(&cur[d.x >> 8], 1);
            int p1 = atomicAdd(&cur[d.y >> 8], 1);
            int p2 = atomicAdd(&cur[d.z >> 8], 1);
            int p3 = atomicAdd(&cur[d.w >> 8], 1);
            binned[p0] = (unsigned)s.x | ((unsigned)(d.x & 255) << 16);
            binned[p1] = (unsigned)s.y | ((unsigned)(d.y & 255) << 16);
            binned[p2] = (unsigned)s.z | ((unsigned)(d.z & 255) << 16);
            binned[p3] = (unsigned)s.w | ((unsigned)(d.w & 255) << 16);
        } else {
            for (int k = idx; k < e && k < idx + 4; ++k) {
                int d = dst[k];
                int p = atomicAdd(&cur[d >> 8], 1);
                binned[p] = (unsigned)src[k] | ((unsigned)(d & 255) << 16);
            }
        }
    }
}

// ---------------- gemm1 body: [n x 128] fp32 @ Wt1 -> fp8 raw (no scale) ----------------

__device__ __forceinline__ void gemm1_body(const float* __restrict__ A, const _Float16* __restrict__ Wt,
                                           unsigned char* __restrict__ C, int n, int blk) {
    int wave = threadIdx.x >> 6;
    int lane = threadIdx.x & 63;
    int base = blk * 64 + wave * 16;
    if (base >= n) return;
    int ma = lane & 15;
    int kb = lane >> 4;

    f32x4 acc[8];
#pragma unroll
    for (int t = 0; t < 8; ++t) acc[t] = (f32x4){0.f, 0.f, 0.f, 0.f};

#pragma unroll
    for (int kk = 0; kk < 4; ++kk) {
        int k0 = kk * 32 + kb * 8;
        const float* ap = A + (size_t)(base + ma) * CH + k0;
        float4 a0 = ((const float4*)ap)[0];
        float4 a1 = ((const float4*)ap)[1];
        half8 af;
        af[0] = (_Float16)a0.x; af[1] = (_Float16)a0.y; af[2] = (_Float16)a0.z; af[3] = (_Float16)a0.w;
        af[4] = (_Float16)a1.x; af[5] = (_Float16)a1.y; af[6] = (_Float16)a1.z; af[7] = (_Float16)a1.w;
#pragma unroll
        for (int tn = 0; tn < 8; ++tn) {
            half8 bf = *(const half8*)(Wt + (size_t)(tn * 16 + ma) * CH + k0);
            acc[tn] = __builtin_amdgcn_mfma_f32_16x16x32_f16(af, bf, acc[tn], 0, 0, 0);
        }
    }

    int r0 = base + kb * 4;
#pragma unroll
    for (int tn = 0; tn < 8; ++tn) {
#pragma unroll
        for (int r = 0; r < 4; ++r) {
            C[(size_t)(r0 + r) * CH + tn * 16 + ma] = f32_to_fp8(acc[tn][r]);
        }
    }
}

// ---------------- phase 4 fused: bucket build (blocks 0..NBINS) + gemm1 (rest) ----------------

__global__ __launch_bounds__(256) void bucket_gemm1_k(const unsigned int* __restrict__ binned,
                                                      const int* __restrict__ bin_start,
                                                      int* __restrict__ cursor, int* __restrict__ csr,
                                                      const float* __restrict__ x, const _Float16* __restrict__ Wt1,
                                                      unsigned char* __restrict__ h1, int n) {
    if ((int)blockIdx.x < NBINS) {
        __shared__ int cur2[256];
        cur2[threadIdx.x] = 0;
        __syncthreads();
        int lo = bin_start[blockIdx.x], hi = bin_start[blockIdx.x + 1];
        for (int i = lo + threadIdx.x; i < hi; i += 256) {
            unsigned int p = binned[i];
            int local = p >> 16;
            int node = (blockIdx.x << 8) | local;
            int pos = atomicAdd(&cur2[local], 1);
            if (pos < CAP) csr[(size_t)node * CAP + pos] = (int)(p & 0xFFFFu);
        }
        __syncthreads();
        int node = blockIdx.x * 256 + threadIdx.x;
        if (node < n) cursor[node] = cur2[threadIdx.x];
    } else {
        gemm1_body(x, Wt1, h1, n, blockIdx.x - NBINS);
    }
}

// ---------------- phase 5 fused: aggregate1 (fp8 gather, per-src dinv) + gemm2 -> fp8 prescaled h2 ----------------
// Block = 16 nodes (N % 16 == 0). Gather phase: 16 lanes/node, 8 ch/lane (uint2 = 8 fp8).
// GEMM phase: agg rows in LDS (pad +8 halves -> 2-way-free banks), 4 waves x 2 col-tiles MFMA.

__global__ __launch_bounds__(256) void agg1_gemm2_k(const unsigned char* __restrict__ h1,
                                                    const int* __restrict__ cursor, const int* __restrict__ csr,
                                                    const float* __restrict__ b1, const _Float16* __restrict__ Wt2,
                                                    unsigned char* __restrict__ h2, int n) {
    __shared__ _Float16 xs[16][136];
    int local = threadIdx.x >> 4;
    int node = blockIdx.x * 16 + local;
    int lane = threadIdx.x & 15;
    const uint2* H = (const uint2*)h1;

    int deg = cursor[node];
    float dv = rsqrtf((float)deg + 1.0f);
    int degc = deg > CAP ? CAP : deg;

    float acc[8];
    {
        float t[8];
        unpack_fp8x8(H[(size_t)node * 16 + lane], t);
#pragma unroll
        for (int j = 0; j < 8; ++j) acc[j] = t[j] * dv;   // self: dinv_v * h1_v (h1 raw)
    }
    const int4* row4 = (const int4*)(csr + (size_t)node * CAP);
    int i = 0;
    for (; i + 4 <= degc; i += 4) {
        int4 s4 = row4[i >> 2];
        uint2 v0 = H[(size_t)s4.x * 16 + lane];
        uint2 v1 = H[(size_t)s4.y * 16 + lane];
        uint2 v2 = H[(size_t)s4.z * 16 + lane];
        uint2 v3 = H[(size_t)s4.w * 16 + lane];
        float w0 = rsqrtf((float)cursor[s4.x] + 1.0f);
        float w1 = rsqrtf((float)cursor[s4.y] + 1.0f);
        float w2 = rsqrtf((float)cursor[s4.z] + 1.0f);
        float w3 = rsqrtf((float)cursor[s4.w] + 1.0f);
        float t0[8], t1[8], t2[8], t3[8];
        unpack_fp8x8(v0, t0); unpack_fp8x8(v1, t1); unpack_fp8x8(v2, t2); unpack_fp8x8(v3, t3);
#pragma unroll
        for (int j = 0; j < 8; ++j) {
            acc[j] = fmaf(t0[j], w0, acc[j]);
            acc[j] = fmaf(t1[j], w1, acc[j]);
            acc[j] = fmaf(t2[j], w2, acc[j]);
            acc[j] = fmaf(t3[j], w3, acc[j]);
        }
    }
    for (; i < degc; ++i) {
        int s = csr[(size_t)node * CAP + i];
        float w = rsqrtf((float)cursor[s] + 1.0f);
        float t[8];
        unpack_fp8x8(H[(size_t)s * 16 + lane], t);
#pragma unroll
        for (int j = 0; j < 8; ++j) acc[j] = fmaf(t[j], w, acc[j]);
    }

    // bias + relu -> LDS fp16
    float4 bb0 = ((const float4*)b1)[2 * lane];
    float4 bb1 = ((const float4*)b1)[2 * lane + 1];
    float rr[8];
    rr[0] = fmaxf(fmaf(acc[0], dv, bb0.x), 0.f);
    rr[1] = fmaxf(fmaf(acc[1], dv, bb0.y), 0.f);
    rr[2] = fmaxf(fmaf(acc[2], dv, bb0.z), 0.f);
    rr[3] = fmaxf(fmaf(acc[3], dv, bb0.w), 0.f);
    rr[4] = fmaxf(fmaf(acc[4], dv, bb1.x), 0.f);
    rr[5] = fmaxf(fmaf(acc[5], dv, bb1.y), 0.f);
    rr[6] = fmaxf(fmaf(acc[6], dv, bb1.z), 0.f);
    rr[7] = fmaxf(fmaf(acc[7], dv, bb1.w), 0.f);
    half8 hv;
#pragma unroll
    for (int j = 0; j < 8; ++j) hv[j] = (_Float16)rr[j];
    *(half8*)&xs[local][lane * 8] = hv;
    __syncthreads();

    // GEMM: 16x128 @ Wt2 (each wave: 2 col-tiles)
    int wave = threadIdx.x >> 6;
    int l = threadIdx.x & 63;
    int ma = l & 15;
    int kb = l >> 4;
    f32x4 acc2[2];
    acc2[0] = (f32x4){0.f, 0.f, 0.f, 0.f};
    acc2[1] = (f32x4){0.f, 0.f, 0.f, 0.f};
#pragma unroll
    for (int kk = 0; kk < 4; ++kk) {
        int k0 = kk * 32 + kb * 8;
        half8 af = *(const half8*)&xs[ma][k0];
#pragma unroll
        for (int t = 0; t < 2; ++t) {
            int tn = wave * 2 + t;
            half8 bf = *(const half8*)(Wt2 + (size_t)(tn * 16 + ma) * CH + k0);
            acc2[t] = __builtin_amdgcn_mfma_f32_16x16x32_f16(af, bf, acc2[t], 0, 0, 0);
        }
    }
    int gr0 = blockIdx.x * 16 + kb * 4;
    float dv2[4];
#pragma unroll
    for (int r = 0; r < 4; ++r) dv2[r] = rsqrtf((float)cursor[gr0 + r] + 1.0f);
#pragma unroll
    for (int t = 0; t < 2; ++t) {
        int tn = wave * 2 + t;
#pragma unroll
        for (int r = 0; r < 4; ++r) {
            h2[(size_t)(gr0 + r) * CH + tn * 16 + ma] = f32_to_fp8(acc2[t][r] * dv2[r]);
        }
    }
}

// ---------------- phase 6: aggregate2 (fp8 prescaled gather) -> fp16 agg2 ----------------

__global__ __launch_bounds__(256) void aggregate2_k(const unsigned char* __restrict__ ht,
                                                    const int* __restrict__ cursor, const int* __restrict__ csr,
                                                    const float* __restrict__ bias, __half* __restrict__ out, int n) {
    int node = blockIdx.x * 16 + (threadIdx.x >> 4);
    int lane = threadIdx.x & 15;
    const uint2* H = (const uint2*)ht;
    int deg = cursor[node];
    float dv = rsqrtf((float)deg + 1.0f);
    int degc = deg > CAP ? CAP : deg;

    float acc[8];
    unpack_fp8x8(H[(size_t)node * 16 + lane], acc);   // self (prescaled)

    const int4* row4 = (const int4*)(csr + (size_t)node * CAP);
    int i = 0;
    for (; i + 4 <= degc; i += 4) {
        int4 s4 = row4[i >> 2];
        uint2 v0 = H[(size_t)s4.x * 16 + lane];
        uint2 v1 = H[(size_t)s4.y * 16 + lane];
        uint2 v2 = H[(size_t)s4.z * 16 + lane];
        uint2 v3 = H[(size_t)s4.w * 16 + lane];
        float t0[8], t1[8], t2[8], t3[8];
        unpack_fp8x8(v0, t0); unpack_fp8x8(v1, t1); unpack_fp8x8(v2, t2); unpack_fp8x8(v3, t3);
#pragma unroll
        for (int j = 0; j < 8; ++j) acc[j] += (t0[j] + t1[j]) + (t2[j] + t3[j]);
    }
    for (; i < degc; ++i) {
        int s = csr[(size_t)node * CAP + i];
        float t[8];
        unpack_fp8x8(H[(size_t)s * 16 + lane], t);
#pragma unroll
        for (int j = 0; j < 8; ++j) acc[j] += t[j];
    }

    float4 b0 = ((const float4*)bias)[2 * lane];
    float4 b1 = ((const float4*)bias)[2 * lane + 1];
    float r0 = fmaxf(fmaf(acc[0], dv, b0.x), 0.f);
    float r1 = fmaxf(fmaf(acc[1], dv, b0.y), 0.f);
    float r2 = fmaxf(fmaf(acc[2], dv, b0.z), 0.f);
    float r3 = fmaxf(fmaf(acc[3], dv, b0.w), 0.f);
    float r4 = fmaxf(fmaf(acc[4], dv, b1.x), 0.f);
    float r5 = fmaxf(fmaf(acc[5], dv, b1.y), 0.f);
    float r6 = fmaxf(fmaf(acc[6], dv, b1.z), 0.f);
    float r7 = fmaxf(fmaf(acc[7], dv, b1.w), 0.f);
    __half2 q0 = __floats2half2_rn(r0, r1);
    __half2 q1 = __floats2half2_rn(r2, r3);
    __half2 q2 = __floats2half2_rn(r4, r5);
    __half2 q3 = __floats2half2_rn(r6, r7);
    uint4 pk;
    pk.x = *(const unsigned int*)&q0;
    pk.y = *(const unsigned int*)&q1;
    pk.z = *(const unsigned int*)&q2;
    pk.w = *(const unsigned int*)&q3;
    ((uint4*)out)[(size_t)node * 16 + lane] = pk;
}

// ---------------- fused mean-pool + FC + sigmoid ----------------

__global__ __launch_bounds__(128) void pool_fc_k(const __half* __restrict__ h, const int* __restrict__ gstart,
                                                 const float* __restrict__ Wfc, const float* __restrict__ bfc,
                                                 float* __restrict__ out) {
    __shared__ float ps[CH];
    int g = blockIdx.x;
    int t = threadIdx.x;
    int beg = gstart[g], end = gstart[g + 1];
    int c = end - beg;
    float s = 0.f;
    for (int i = 0; i < c; ++i) s += __half2float(h[(size_t)(beg + i) * CH + t]);
    ps[t] = s / fmaxf((float)c, 1.0f);
    __syncthreads();
    if (t < OCH) {
        float acc = bfc[t];
#pragma unroll 8
        for (int k = 0; k < CH; ++k) acc = fmaf(ps[k], Wfc[k * OCH + t], acc);
        out[(size_t)g * OCH + t] = 1.0f / (1.0f + expf(-acc));
    }
}

extern "C" void kernel_launch(void* const* d_in, const int* in_sizes, int n_in,
                              void* d_out, int out_size, void* d_ws, size_t ws_size,
                              hipStream_t stream) {
    const float* x    = (const float*)d_in[0];
    const int*   edge = (const int*)d_in[1];
    const int*   batch= (const int*)d_in[2];
    const float* W1   = (const float*)d_in[3];
    const float* b1   = (const float*)d_in[4];
    const float* W2   = (const float*)d_in[5];
    const float* b2   = (const float*)d_in[6];
    const float* Wfc  = (const float*)d_in[7];
    const float* bfc  = (const float*)d_in[8];
    float* out = (float*)d_out;

    const int N = NN;
    const int E = in_sizes[1] / 2;
    const int* src = edge;
    const int* dst = edge + E;

    // workspace layout (16B alignment preserved in order)
    unsigned char* h1 = (unsigned char*)d_ws;            // N*CH fp8
    unsigned char* h2 = h1 + (size_t)N * CH;             // N*CH fp8
    __half* agg2      = (__half*)(h2 + (size_t)N * CH);  // N*CH fp16
    _Float16* Wt1     = (_Float16*)(agg2 + (size_t)N * CH); // CH*CH
    _Float16* Wt2     = Wt1 + CH * CH;                   // CH*CH
    int* cursor       = (int*)(Wt2 + CH * CH);           // N
    int* gstart       = cursor + N;                      // NG+4
    int* csr          = gstart + NG + 4;                 // N*CAP
    int* tableT       = csr + (size_t)N * CAP;           // NBINS*HB
    int* binsum       = tableT + NBINS * HB;             // pad 256
    int* bin_start    = binsum + 256;                    // pad 208
    unsigned int* binned = (unsigned int*)(bin_start + 208);  // E packed words

    const int G = (N + 63) / 64;   // 782 gemm blocks

    hist_init_k<<<HB + 66, 256, 0, stream>>>(dst, E, tableT, batch, N, gstart, W1, W2, Wt1, Wt2);
    scanA_k<<<49, 256, 0, stream>>>(tableT, binsum);
    scanB_k<<<1, 256, 0, stream>>>(binsum, bin_start);
    scatter_k<<<HB, 256, 0, stream>>>(src, dst, E, tableT, bin_start, binned);
    bucket_gemm1_k<<<NBINS + G, 256, 0, stream>>>(binned, bin_start, cursor, csr, x, Wt1, h1, N);
    agg1_gemm2_k<<<N / 16, 256, 0, stream>>>(h1, cursor, csr, b1, Wt2, h2, N);
    aggregate2_k<<<N / 16, 256, 0, stream>>>(h2, cursor, csr, b2, agg2, N);
    pool_fc_k<<<NG, 128, 0, stream>>>(agg2, gstart, Wfc, bfc, out);
}

// Round 12
// 113.703 us; speedup vs baseline: 3.4259x; 1.1136x over previous
//
#include <hip/hip_runtime.h>
#include <hip/hip_fp16.h>
#include <math.h>

#define NN 50000
#define CH 128
#define NG 512
#define OCH 16
#define CAP 64        // bucket capacity per node; deg ~ Poisson(12), P(>=64) ~ 1e-30
#define NBINS 196     // bin = dst >> 8 (256 nodes per bin)
#define HB 147        // hist/scatter blocks, 4096 edges each

typedef _Float16 half8 __attribute__((ext_vector_type(8)));
typedef float f32x4 __attribute__((ext_vector_type(4)));
typedef float f32x2 __attribute__((ext_vector_type(2)));

// ---- fp8 e4m3 helpers (HW cvt, gfx940+ insts; OCP on gfx950) ----

__device__ __forceinline__ void unpack_fp8x8(uint2 v, float* o) {
    f32x2 a = __builtin_amdgcn_cvt_pk_f32_fp8((int)v.x, false);
    f32x2 b = __builtin_amdgcn_cvt_pk_f32_fp8((int)v.x, true);
    f32x2 c = __builtin_amdgcn_cvt_pk_f32_fp8((int)v.y, false);
    f32x2 d = __builtin_amdgcn_cvt_pk_f32_fp8((int)v.y, true);
    o[0] = a[0]; o[1] = a[1]; o[2] = b[0]; o[3] = b[1];
    o[4] = c[0]; o[5] = c[1]; o[6] = d[0]; o[7] = d[1];
}

__device__ __forceinline__ unsigned char f32_to_fp8(float v) {
    int r = __builtin_amdgcn_cvt_pk_fp8_f32(v, v, 0, false);
    return (unsigned char)(r & 0xFF);
}

// ---------------- gemm1 body: [n x 128] fp32 @ Wt1 -> fp8 raw ----------------

__device__ __forceinline__ void gemm1_body(const float* __restrict__ A, const _Float16* __restrict__ Wt,
                                           unsigned char* __restrict__ C, int n, int blk) {
    int wave = threadIdx.x >> 6;
    int lane = threadIdx.x & 63;
    int base = blk * 64 + wave * 16;
    if (base >= n) return;
    int ma = lane & 15;
    int kb = lane >> 4;

    f32x4 acc[8];
#pragma unroll
    for (int t = 0; t < 8; ++t) acc[t] = (f32x4){0.f, 0.f, 0.f, 0.f};

#pragma unroll
    for (int kk = 0; kk < 4; ++kk) {
        int k0 = kk * 32 + kb * 8;
        const float* ap = A + (size_t)(base + ma) * CH + k0;
        float4 a0 = ((const float4*)ap)[0];
        float4 a1 = ((const float4*)ap)[1];
        half8 af;
        af[0] = (_Float16)a0.x; af[1] = (_Float16)a0.y; af[2] = (_Float16)a0.z; af[3] = (_Float16)a0.w;
        af[4] = (_Float16)a1.x; af[5] = (_Float16)a1.y; af[6] = (_Float16)a1.z; af[7] = (_Float16)a1.w;
#pragma unroll
        for (int tn = 0; tn < 8; ++tn) {
            half8 bf = *(const half8*)(Wt + (size_t)(tn * 16 + ma) * CH + k0);
            acc[tn] = __builtin_amdgcn_mfma_f32_16x16x32_f16(af, bf, acc[tn], 0, 0, 0);
        }
    }

    int r0 = base + kb * 4;
#pragma unroll
    for (int tn = 0; tn < 8; ++tn) {
#pragma unroll
        for (int r = 0; r < 4; ++r) {
            C[(size_t)(r0 + r) * CH + tn * 16 + ma] = f32_to_fp8(acc[tn][r]);
        }
    }
}

// ---------------- K1 (fused): hist (0..HB) + init (HB..HB+66) + gemm1 (rest) ----------------

__global__ __launch_bounds__(256) void k1_hist_init_gemm1_k(const int* __restrict__ dst, int e, int* __restrict__ tableT,
                                                            const int* __restrict__ batch, int n, int* __restrict__ gstart,
                                                            const float* __restrict__ W1, const float* __restrict__ W2,
                                                            _Float16* __restrict__ Wt1, _Float16* __restrict__ Wt2,
                                                            const float* __restrict__ x, unsigned char* __restrict__ h1) {
    if ((int)blockIdx.x < HB) {
        __shared__ int hist[NBINS];
        for (int i = threadIdx.x; i < NBINS; i += 256) hist[i] = 0;
        __syncthreads();
#pragma unroll
        for (int j = 0; j < 4; ++j) {
            int idx = blockIdx.x * 4096 + j * 1024 + threadIdx.x * 4;
            if (idx + 3 < e) {
                int4 d = *(const int4*)&dst[idx];
                atomicAdd(&hist[d.x >> 8], 1);
                atomicAdd(&hist[d.y >> 8], 1);
                atomicAdd(&hist[d.z >> 8], 1);
                atomicAdd(&hist[d.w >> 8], 1);
            } else {
                for (int k = idx; k < e && k < idx + 4; ++k) atomicAdd(&hist[dst[k] >> 8], 1);
            }
        }
        __syncthreads();
        for (int i = threadIdx.x; i < NBINS; i += 256) tableT[i * HB + blockIdx.x] = hist[i];
    } else if ((int)blockIdx.x < HB + 66) {
        int i = ((int)blockIdx.x - HB) * 256 + threadIdx.x;
        if (i <= NG) {
            int lo = 0, hi = n;
            while (lo < hi) {
                int mid = (lo + hi) >> 1;
                if (batch[mid] < i) lo = mid + 1; else hi = mid;
            }
            gstart[i] = lo;
        }
        if (i < CH * CH) {
            int k = i >> 7, c = i & 127;
            Wt1[c * CH + k] = (_Float16)W1[i];
            Wt2[c * CH + k] = (_Float16)W2[i];
        }
    } else {
        gemm1_body(x, Wt1, h1, n, blockIdx.x - (HB + 66));
    }
}

// ---------------- phase 2a: per-bin wave scan over HB block counts (196 waves) ----------------

__global__ __launch_bounds__(256) void scanA_k(int* __restrict__ tableT, int* __restrict__ binsum) {
    int w = threadIdx.x >> 6, lane = threadIdx.x & 63;
    int bin = blockIdx.x * 4 + w;
    int* row = tableT + bin * HB;
    int b3 = lane * 3;
    int v0 = (b3     < HB) ? row[b3]     : 0;
    int v1 = (b3 + 1 < HB) ? row[b3 + 1] : 0;
    int v2 = (b3 + 2 < HB) ? row[b3 + 2] : 0;
    int s = v0 + v1 + v2;
    int x = s;
#pragma unroll
    for (int off = 1; off < 64; off <<= 1) {
        int y = __shfl_up(x, off);
        if (lane >= off) x += y;
    }
    int excl = x - s;
    if (b3     < HB) row[b3]     = excl;
    if (b3 + 1 < HB) row[b3 + 1] = excl + v0;
    if (b3 + 2 < HB) row[b3 + 2] = excl + v0 + v1;
    if (lane == 63) binsum[bin] = x;
}

// ---------------- phase 2b: scan 196 bin totals -> bin_start ----------------

__global__ __launch_bounds__(256) void scanB_k(const int* __restrict__ binsum, int* __restrict__ bin_start) {
    __shared__ int s[256];
    int t = threadIdx.x;
    int v = (t < NBINS) ? binsum[t] : 0;
    s[t] = v;
    __syncthreads();
    for (int off = 1; off < 256; off <<= 1) {
        int u = (t >= off) ? s[t - off] : 0;
        __syncthreads();
        s[t] += u;
        __syncthreads();
    }
    if (t < NBINS) bin_start[t] = s[t] - v;
    if (t == NBINS - 1) bin_start[NBINS] = s[t];
}

// ---------------- phase 3: scatter edges into bin-contiguous packed words ----------------

__global__ __launch_bounds__(256) void scatter_k(const int* __restrict__ src, const int* __restrict__ dst, int e,
                                                 const int* __restrict__ tableT, const int* __restrict__ bin_start,
                                                 unsigned int* __restrict__ binned) {
    __shared__ int cur[NBINS];
    for (int i = threadIdx.x; i < NBINS; i += 256) cur[i] = bin_start[i] + tableT[i * HB + blockIdx.x];
    __syncthreads();
#pragma unroll
    for (int j = 0; j < 4; ++j) {
        int idx = blockIdx.x * 4096 + j * 1024 + threadIdx.x * 4;
        if (idx + 3 < e) {
            int4 d = *(const int4*)&dst[idx];
            int4 s = *(const int4*)&src[idx];
            int p0 = atomicAdd(&cur[d.x >> 8], 1);
            int p1 = atomicAdd(&cur[d.y >> 8], 1);
            int p2 = atomicAdd(&cur[d.z >> 8], 1);
            int p3 = atomicAdd(&cur[d.w >> 8], 1);
            binned[p0] = (unsigned)s.x | ((unsigned)(d.x & 255) << 16);
            binned[p1] = (unsigned)s.y | ((unsigned)(d.y & 255) << 16);
            binned[p2] = (unsigned)s.z | ((unsigned)(d.z & 255) << 16);
            binned[p3] = (unsigned)s.w | ((unsigned)(d.w & 255) << 16);
        } else {
            for (int k = idx; k < e && k < idx + 4; ++k) {
                int d = dst[k];
                int p = atomicAdd(&cur[d >> 8], 1);
                binned[p] = (unsigned)src[k] | ((unsigned)(d & 255) << 16);
            }
        }
    }
}

// ---------------- phase 4: bucket build (csr + cursor) ----------------

__global__ __launch_bounds__(256) void bucket_k(const unsigned int* __restrict__ binned,
                                                const int* __restrict__ bin_start,
                                                int* __restrict__ cursor, int* __restrict__ csr, int n) {
    __shared__ int cur2[256];
    cur2[threadIdx.x] = 0;
    __syncthreads();
    int lo = bin_start[blockIdx.x], hi = bin_start[blockIdx.x + 1];
    for (int i = lo + threadIdx.x; i < hi; i += 256) {
        unsigned int p = binned[i];
        int local = p >> 16;
        int node = ((int)blockIdx.x << 8) | local;
        int pos = atomicAdd(&cur2[local], 1);
        if (pos < CAP) csr[(size_t)node * CAP + pos] = (int)(p & 0xFFFFu);
    }
    __syncthreads();
    int node = blockIdx.x * 256 + threadIdx.x;
    if (node < n) cursor[node] = cur2[threadIdx.x];
}

// ---------------- phase 5 fused: aggregate1 (fp8 gather, 8-deep) + gemm2 -> fp8 prescaled h2 ----------------

__global__ __launch_bounds__(256) void agg1_gemm2_k(const unsigned char* __restrict__ h1,
                                                    const int* __restrict__ cursor, const int* __restrict__ csr,
                                                    const float* __restrict__ b1, const _Float16* __restrict__ Wt2,
                                                    unsigned char* __restrict__ h2, int n) {
    __shared__ _Float16 xs[16][136];
    int local = threadIdx.x >> 4;
    int node = blockIdx.x * 16 + local;
    int lane = threadIdx.x & 15;
    const uint2* H = (const uint2*)h1;

    int deg = cursor[node];
    float dv = rsqrtf((float)deg + 1.0f);
    int degc = deg > CAP ? CAP : deg;

    float acc[8];
    {
        float t[8];
        unpack_fp8x8(H[(size_t)node * 16 + lane], t);
#pragma unroll
        for (int j = 0; j < 8; ++j) acc[j] = t[j] * dv;   // self: dinv_v * h1_v
    }
    const int4* row4 = (const int4*)(csr + (size_t)node * CAP);
    int i = 0;
    for (; i + 8 <= degc; i += 8) {
        int4 sa = row4[i >> 2];
        int4 sb = row4[(i >> 2) + 1];
        uint2 v0 = H[(size_t)sa.x * 16 + lane];
        uint2 v1 = H[(size_t)sa.y * 16 + lane];
        uint2 v2 = H[(size_t)sa.z * 16 + lane];
        uint2 v3 = H[(size_t)sa.w * 16 + lane];
        uint2 v4 = H[(size_t)sb.x * 16 + lane];
        uint2 v5 = H[(size_t)sb.y * 16 + lane];
        uint2 v6 = H[(size_t)sb.z * 16 + lane];
        uint2 v7 = H[(size_t)sb.w * 16 + lane];
        float w0 = rsqrtf((float)cursor[sa.x] + 1.0f);
        float w1 = rsqrtf((float)cursor[sa.y] + 1.0f);
        float w2 = rsqrtf((float)cursor[sa.z] + 1.0f);
        float w3 = rsqrtf((float)cursor[sa.w] + 1.0f);
        float w4 = rsqrtf((float)cursor[sb.x] + 1.0f);
        float w5 = rsqrtf((float)cursor[sb.y] + 1.0f);
        float w6 = rsqrtf((float)cursor[sb.z] + 1.0f);
        float w7 = rsqrtf((float)cursor[sb.w] + 1.0f);
        float t0[8], t1[8], t2[8], t3[8];
        unpack_fp8x8(v0, t0); unpack_fp8x8(v1, t1); unpack_fp8x8(v2, t2); unpack_fp8x8(v3, t3);
#pragma unroll
        for (int j = 0; j < 8; ++j) {
            acc[j] = fmaf(t0[j], w0, acc[j]);
            acc[j] = fmaf(t1[j], w1, acc[j]);
            acc[j] = fmaf(t2[j], w2, acc[j]);
            acc[j] = fmaf(t3[j], w3, acc[j]);
        }
        unpack_fp8x8(v4, t0); unpack_fp8x8(v5, t1); unpack_fp8x8(v6, t2); unpack_fp8x8(v7, t3);
#pragma unroll
        for (int j = 0; j < 8; ++j) {
            acc[j] = fmaf(t0[j], w4, acc[j]);
            acc[j] = fmaf(t1[j], w5, acc[j]);
            acc[j] = fmaf(t2[j], w6, acc[j]);
            acc[j] = fmaf(t3[j], w7, acc[j]);
        }
    }
    for (; i + 4 <= degc; i += 4) {
        int4 s4 = row4[i >> 2];
        uint2 v0 = H[(size_t)s4.x * 16 + lane];
        uint2 v1 = H[(size_t)s4.y * 16 + lane];
        uint2 v2 = H[(size_t)s4.z * 16 + lane];
        uint2 v3 = H[(size_t)s4.w * 16 + lane];
        float w0 = rsqrtf((float)cursor[s4.x] + 1.0f);
        float w1 = rsqrtf((float)cursor[s4.y] + 1.0f);
        float w2 = rsqrtf((float)cursor[s4.z] + 1.0f);
        float w3 = rsqrtf((float)cursor[s4.w] + 1.0f);
        float t0[8], t1[8], t2[8], t3[8];
        unpack_fp8x8(v0, t0); unpack_fp8x8(v1, t1); unpack_fp8x8(v2, t2); unpack_fp8x8(v3, t3);
#pragma unroll
        for (int j = 0; j < 8; ++j) {
            acc[j] = fmaf(t0[j], w0, acc[j]);
            acc[j] = fmaf(t1[j], w1, acc[j]);
            acc[j] = fmaf(t2[j], w2, acc[j]);
            acc[j] = fmaf(t3[j], w3, acc[j]);
        }
    }
    for (; i < degc; ++i) {
        int s = csr[(size_t)node * CAP + i];
        float w = rsqrtf((float)cursor[s] + 1.0f);
        float t[8];
        unpack_fp8x8(H[(size_t)s * 16 + lane], t);
#pragma unroll
        for (int j = 0; j < 8; ++j) acc[j] = fmaf(t[j], w, acc[j]);
    }

    // bias + relu -> LDS fp16
    float4 bb0 = ((const float4*)b1)[2 * lane];
    float4 bb1 = ((const float4*)b1)[2 * lane + 1];
    float rr[8];
    rr[0] = fmaxf(fmaf(acc[0], dv, bb0.x), 0.f);
    rr[1] = fmaxf(fmaf(acc[1], dv, bb0.y), 0.f);
    rr[2] = fmaxf(fmaf(acc[2], dv, bb0.z), 0.f);
    rr[3] = fmaxf(fmaf(acc[3], dv, bb0.w), 0.f);
    rr[4] = fmaxf(fmaf(acc[4], dv, bb1.x), 0.f);
    rr[5] = fmaxf(fmaf(acc[5], dv, bb1.y), 0.f);
    rr[6] = fmaxf(fmaf(acc[6], dv, bb1.z), 0.f);
    rr[7] = fmaxf(fmaf(acc[7], dv, bb1.w), 0.f);
    half8 hv;
#pragma unroll
    for (int j = 0; j < 8; ++j) hv[j] = (_Float16)rr[j];
    *(half8*)&xs[local][lane * 8] = hv;
    __syncthreads();

    // GEMM: 16x128 @ Wt2 (each wave: 2 col-tiles), prescaled fp8 out
    int wave = threadIdx.x >> 6;
    int l = threadIdx.x & 63;
    int ma = l & 15;
    int kb = l >> 4;
    f32x4 acc2[2];
    acc2[0] = (f32x4){0.f, 0.f, 0.f, 0.f};
    acc2[1] = (f32x4){0.f, 0.f, 0.f, 0.f};
#pragma unroll
    for (int kk = 0; kk < 4; ++kk) {
        int k0 = kk * 32 + kb * 8;
        half8 af = *(const half8*)&xs[ma][k0];
#pragma unroll
        for (int t = 0; t < 2; ++t) {
            int tn = wave * 2 + t;
            half8 bf = *(const half8*)(Wt2 + (size_t)(tn * 16 + ma) * CH + k0);
            acc2[t] = __builtin_amdgcn_mfma_f32_16x16x32_f16(af, bf, acc2[t], 0, 0, 0);
        }
    }
    int gr0 = blockIdx.x * 16 + kb * 4;
    float dv2[4];
#pragma unroll
    for (int r = 0; r < 4; ++r) dv2[r] = rsqrtf((float)cursor[gr0 + r] + 1.0f);
#pragma unroll
    for (int t = 0; t < 2; ++t) {
        int tn = wave * 2 + t;
#pragma unroll
        for (int r = 0; r < 4; ++r) {
            h2[(size_t)(gr0 + r) * CH + tn * 16 + ma] = f32_to_fp8(acc2[t][r] * dv2[r]);
        }
    }
}

// ---------------- phase 6 fused: aggregate2 (fp8 prescaled gather) + mean-pool + FC + sigmoid ----------------
// Block = 1 graph. 16 groups x 16 lanes; groups stride the graph's contiguous node range.

__global__ __launch_bounds__(256) void agg2_pool_fc_k(const unsigned char* __restrict__ h2,
                                                      const int* __restrict__ cursor, const int* __restrict__ csr,
                                                      const float* __restrict__ b2, const int* __restrict__ gstart,
                                                      const float* __restrict__ Wfc, const float* __restrict__ bfc,
                                                      float* __restrict__ out) {
    __shared__ float psum[16][128];
    int g = blockIdx.x;
    int group = threadIdx.x >> 4;
    int lane = threadIdx.x & 15;
    int beg = gstart[g], end = gstart[g + 1];
    int c = end - beg;
    const uint2* H = (const uint2*)h2;

    float4 bb0 = ((const float4*)b2)[2 * lane];
    float4 bb1 = ((const float4*)b2)[2 * lane + 1];
    float bias[8] = {bb0.x, bb0.y, bb0.z, bb0.w, bb1.x, bb1.y, bb1.z, bb1.w};

    float racc[8] = {0.f, 0.f, 0.f, 0.f, 0.f, 0.f, 0.f, 0.f};

    for (int node = beg + group; node < end; node += 16) {
        int deg = cursor[node];
        float dv = rsqrtf((float)deg + 1.0f);
        int degc = deg > CAP ? CAP : deg;

        float acc[8];
        unpack_fp8x8(H[(size_t)node * 16 + lane], acc);   // self (prescaled)

        const int4* row4 = (const int4*)(csr + (size_t)node * CAP);
        int i = 0;
        for (; i + 8 <= degc; i += 8) {
            int4 sa = row4[i >> 2];
            int4 sb = row4[(i >> 2) + 1];
            uint2 v0 = H[(size_t)sa.x * 16 + lane];
            uint2 v1 = H[(size_t)sa.y * 16 + lane];
            uint2 v2 = H[(size_t)sa.z * 16 + lane];
            uint2 v3 = H[(size_t)sa.w * 16 + lane];
            uint2 v4 = H[(size_t)sb.x * 16 + lane];
            uint2 v5 = H[(size_t)sb.y * 16 + lane];
            uint2 v6 = H[(size_t)sb.z * 16 + lane];
            uint2 v7 = H[(size_t)sb.w * 16 + lane];
            float t0[8], t1[8], t2[8], t3[8];
            unpack_fp8x8(v0, t0); unpack_fp8x8(v1, t1); unpack_fp8x8(v2, t2); unpack_fp8x8(v3, t3);
#pragma unroll
            for (int j = 0; j < 8; ++j) acc[j] += (t0[j] + t1[j]) + (t2[j] + t3[j]);
            unpack_fp8x8(v4, t0); unpack_fp8x8(v5, t1); unpack_fp8x8(v6, t2); unpack_fp8x8(v7, t3);
#pragma unroll
            for (int j = 0; j < 8; ++j) acc[j] += (t0[j] + t1[j]) + (t2[j] + t3[j]);
        }
        for (; i + 4 <= degc; i += 4) {
            int4 s4 = row4[i >> 2];
            uint2 v0 = H[(size_t)s4.x * 16 + lane];
            uint2 v1 = H[(size_t)s4.y * 16 + lane];
            uint2 v2 = H[(size_t)s4.z * 16 + lane];
            uint2 v3 = H[(size_t)s4.w * 16 + lane];
            float t0[8], t1[8], t2[8], t3[8];
            unpack_fp8x8(v0, t0); unpack_fp8x8(v1, t1); unpack_fp8x8(v2, t2); unpack_fp8x8(v3, t3);
#pragma unroll
            for (int j = 0; j < 8; ++j) acc[j] += (t0[j] + t1[j]) + (t2[j] + t3[j]);
        }
        for (; i < degc; ++i) {
            int s = csr[(size_t)node * CAP + i];
            float t[8];
            unpack_fp8x8(H[(size_t)s * 16 + lane], t);
#pragma unroll
            for (int j = 0; j < 8; ++j) acc[j] += t[j];
        }

#pragma unroll
        for (int j = 0; j < 8; ++j) racc[j] += fmaxf(fmaf(acc[j], dv, bias[j]), 0.f);
    }

#pragma unroll
    for (int j = 0; j < 8; ++j) psum[group][lane * 8 + j] = racc[j];
    __syncthreads();

    int t = threadIdx.x;
    if (t < CH) {
        float s = 0.f;
#pragma unroll
        for (int gg = 0; gg < 16; ++gg) s += psum[gg][t];
        psum[0][t] = s / fmaxf((float)c, 1.0f);
    }
    __syncthreads();
    if (t < OCH) {
        float acc = bfc[t];
#pragma unroll 8
        for (int k = 0; k < CH; ++k) acc = fmaf(psum[0][k], Wfc[k * OCH + t], acc);
        out[(size_t)g * OCH + t] = 1.0f / (1.0f + expf(-acc));
    }
}

extern "C" void kernel_launch(void* const* d_in, const int* in_sizes, int n_in,
                              void* d_out, int out_size, void* d_ws, size_t ws_size,
                              hipStream_t stream) {
    const float* x    = (const float*)d_in[0];
    const int*   edge = (const int*)d_in[1];
    const int*   batch= (const int*)d_in[2];
    const float* W1   = (const float*)d_in[3];
    const float* b1   = (const float*)d_in[4];
    const float* W2   = (const float*)d_in[5];
    const float* b2   = (const float*)d_in[6];
    const float* Wfc  = (const float*)d_in[7];
    const float* bfc  = (const float*)d_in[8];
    float* out = (float*)d_out;

    const int N = NN;
    const int E = in_sizes[1] / 2;
    const int* src = edge;
    const int* dst = edge + E;

    // workspace layout (16B alignment preserved in order)
    unsigned char* h1 = (unsigned char*)d_ws;            // N*CH fp8
    unsigned char* h2 = h1 + (size_t)N * CH;             // N*CH fp8
    _Float16* Wt1     = (_Float16*)(h2 + (size_t)N * CH);// CH*CH
    _Float16* Wt2     = Wt1 + CH * CH;                   // CH*CH
    int* cursor       = (int*)(Wt2 + CH * CH);           // N
    int* gstart       = cursor + N;                      // NG+4
    int* csr          = gstart + NG + 4;                 // N*CAP
    int* tableT       = csr + (size_t)N * CAP;           // NBINS*HB
    int* binsum       = tableT + NBINS * HB;             // pad 256
    int* bin_start    = binsum + 256;                    // pad 208
    unsigned int* binned = (unsigned int*)(bin_start + 208);  // E packed words

    const int G = (N + 63) / 64;   // 782 gemm blocks

    k1_hist_init_gemm1_k<<<HB + 66 + G, 256, 0, stream>>>(dst, E, tableT, batch, N, gstart,
                                                          W1, W2, Wt1, Wt2, x, h1);
    scanA_k<<<49, 256, 0, stream>>>(tableT, binsum);
    scanB_k<<<1, 256, 0, stream>>>(binsum, bin_start);
    scatter_k<<<HB, 256, 0, stream>>>(src, dst, E, tableT, bin_start, binned);
    bucket_k<<<NBINS, 256, 0, stream>>>(binned, bin_start, cursor, csr, N);
    agg1_gemm2_k<<<N / 16, 256, 0, stream>>>(h1, cursor, csr, b1, Wt2, h2, N);
    agg2_pool_fc_k<<<NG, 256, 0, stream>>>(h2, cursor, csr, b2, gstart, Wfc, bfc, out);
}